// Round 1
// baseline (8836.659 us; speedup 1.0000x reference)
//
#include <hip/hip_runtime.h>
#include <hip/hip_bf16.h>
#include <math.h>

#define NB 2
#define NN 1024
#define ND 256
#define NHD 4
#define DHE 64
#define NL 6
#define NP (NN + 1)

__device__ __forceinline__ float logsigf(float x) {
    return (x >= 0.f) ? -log1pf(expf(-x)) : (x - log1pf(expf(x)));
}

// ---------------- RoPE tables: cs/sn [B*N, 64] ----------------
__global__ void rope_cs_kernel(const float* __restrict__ kpts, const float* __restrict__ fx,
                               const float* __restrict__ fy, float* __restrict__ cs,
                               float* __restrict__ sn) {
    int idx = blockIdx.x * 256 + threadIdx.x;      // B*N*64
    int row = idx >> 6, j = idx & 63;
    float kx = kpts[row * 2], ky = kpts[row * 2 + 1];
    float f;
    if (j < 32) f = ((kx - 512.f) * (1.f / 512.f)) * fx[j >> 1];
    else        f = ((ky - 384.f) * (1.f / 512.f)) * fy[(j - 32) >> 1];
    cs[idx] = cosf(f);
    sn[idx] = sinf(f);
}

// ---------------- apply rotary in place on qk [B*N, 256] ----------------
__global__ void rope_apply_kernel(float* __restrict__ qk, const float* __restrict__ cs,
                                  const float* __restrict__ sn) {
    int p = blockIdx.x * 256 + threadIdx.x;        // B*N*128 pairs
    int row = p >> 7;
    int d = (p & 127) * 2;
    int dh = d & 63;
    float c0 = cs[row * 64 + dh], c1 = cs[row * 64 + dh + 1];
    float s0 = sn[row * 64 + dh], s1 = sn[row * 64 + dh + 1];
    size_t base = (size_t)row * ND + d;
    float a = qk[base], b = qk[base + 1];
    qk[base]     = a * c0 - b * s0;
    qk[base + 1] = b * c1 + a * s1;
}

// ---------------- generic tiled GEMM: C = (A@W + bias)*scale + res ----------------
__global__ void gemm_kernel(const float* __restrict__ A, const float* __restrict__ W,
                            const float* __restrict__ bias, const float* __restrict__ res,
                            float* __restrict__ C, int M, int K, int Nc, float scale) {
    __shared__ float As[32][33];
    __shared__ float Ws[32][33];
    int tx = threadIdx.x, ty = threadIdx.y;
    int tid = ty * 16 + tx;
    int row0 = blockIdx.y * 32, col0 = blockIdx.x * 32;
    float a00 = 0, a01 = 0, a10 = 0, a11 = 0;
    for (int k0 = 0; k0 < K; k0 += 32) {
#pragma unroll
        for (int l = 0; l < 4; ++l) {
            int idx = tid + l * 256, r = idx >> 5, c = idx & 31;
            As[r][c] = A[(size_t)(row0 + r) * K + k0 + c];
            Ws[r][c] = W[(size_t)(k0 + r) * Nc + col0 + c];
        }
        __syncthreads();
#pragma unroll
        for (int k = 0; k < 32; ++k) {
            float q0 = As[ty * 2][k], q1 = As[ty * 2 + 1][k];
            float w0 = Ws[k][tx * 2], w1 = Ws[k][tx * 2 + 1];
            a00 += q0 * w0; a01 += q0 * w1; a10 += q1 * w0; a11 += q1 * w1;
        }
        __syncthreads();
    }
    int r0 = row0 + ty * 2, c0 = col0 + tx * 2;
    float b0 = bias ? bias[c0] : 0.f, b1 = bias ? bias[c0 + 1] : 0.f;
    float v00 = (a00 + b0) * scale, v01 = (a01 + b1) * scale;
    float v10 = (a10 + b0) * scale, v11 = (a11 + b1) * scale;
    if (res) {
        v00 += res[(size_t)r0 * Nc + c0];       v01 += res[(size_t)r0 * Nc + c0 + 1];
        v10 += res[(size_t)(r0 + 1) * Nc + c0]; v11 += res[(size_t)(r0 + 1) * Nc + c0 + 1];
    }
    C[(size_t)r0 * Nc + c0] = v00;       C[(size_t)r0 * Nc + c0 + 1] = v01;
    C[(size_t)(r0 + 1) * Nc + c0] = v10; C[(size_t)(r0 + 1) * Nc + c0 + 1] = v11;
}

// ---------------- batched scores: S[z,i,j] = scale * sum_k Q[b,i,h*kdim+k]*K[b,j,h*kdim+k] ----
__global__ void scores_kernel(const float* __restrict__ Q, const float* __restrict__ Kt,
                              float* __restrict__ S, int nh, int kdim, float scale) {
    int z = blockIdx.z, b = z / nh, h = z - b * nh;
    int i0 = blockIdx.y * 32, j0 = blockIdx.x * 32;
    const float* Qb = Q + (size_t)b * NN * ND + h * kdim;
    const float* Kb = Kt + (size_t)b * NN * ND + h * kdim;
    float* Sb = S + (size_t)z * NN * NN;
    __shared__ float Qs[32][33], Ks[32][33];
    int tx = threadIdx.x, ty = threadIdx.y, tid = ty * 16 + tx;
    float a00 = 0, a01 = 0, a10 = 0, a11 = 0;
    for (int k0 = 0; k0 < kdim; k0 += 32) {
#pragma unroll
        for (int l = 0; l < 4; ++l) {
            int idx = tid + l * 256, r = idx >> 5, c = idx & 31;
            Qs[r][c] = Qb[(size_t)(i0 + r) * ND + k0 + c];
            Ks[r][c] = Kb[(size_t)(j0 + r) * ND + k0 + c];
        }
        __syncthreads();
#pragma unroll
        for (int k = 0; k < 32; ++k) {
            float q0 = Qs[ty * 2][k], q1 = Qs[ty * 2 + 1][k];
            float k0v = Ks[tx * 2][k], k1v = Ks[tx * 2 + 1][k];
            a00 += q0 * k0v; a01 += q0 * k1v; a10 += q1 * k0v; a11 += q1 * k1v;
        }
        __syncthreads();
    }
    Sb[(size_t)(i0 + ty * 2) * NN + j0 + tx * 2]         = a00 * scale;
    Sb[(size_t)(i0 + ty * 2) * NN + j0 + tx * 2 + 1]     = a01 * scale;
    Sb[(size_t)(i0 + ty * 2 + 1) * NN + j0 + tx * 2]     = a10 * scale;
    Sb[(size_t)(i0 + ty * 2 + 1) * NN + j0 + tx * 2 + 1] = a11 * scale;
}

// ---------------- per-row max & sumexp ----------------
__global__ void rowstats_kernel(const float* __restrict__ S, float* __restrict__ rm,
                                float* __restrict__ rs, int ncols) {
    __shared__ float sb[256];
    int row = blockIdx.x, tid = threadIdx.x;
    const float* p = S + (size_t)row * ncols;
    float m = -1e30f;
    for (int j = tid; j < ncols; j += 256) m = fmaxf(m, p[j]);
    sb[tid] = m; __syncthreads();
    for (int s = 128; s > 0; s >>= 1) { if (tid < s) sb[tid] = fmaxf(sb[tid], sb[tid + s]); __syncthreads(); }
    m = sb[0]; __syncthreads();
    float s = 0;
    for (int j = tid; j < ncols; j += 256) s += expf(p[j] - m);
    sb[tid] = s; __syncthreads();
    for (int st = 128; st > 0; st >>= 1) { if (tid < st) sb[tid] += sb[tid + st]; __syncthreads(); }
    if (tid == 0) { rm[row] = m; rs[row] = sb[0]; }
}

// ---------------- per-col max & sumexp ----------------
__global__ void colstats_kernel(const float* __restrict__ S, float* __restrict__ cm,
                                float* __restrict__ cs, int nrows) {
    int mat = blockIdx.y;
    int j = blockIdx.x * 256 + threadIdx.x;
    const float* p = S + (size_t)mat * nrows * NN + j;
    float m = -1e30f;
    for (int i = 0; i < nrows; ++i) m = fmaxf(m, p[(size_t)i * NN]);
    float s = 0;
    for (int i = 0; i < nrows; ++i) s += expf(p[(size_t)i * NN] - m);
    cm[(size_t)mat * NN + j] = m;
    cs[(size_t)mat * NN + j] = s;
}

// ------- PV with on-the-fly softmax. trans=0: O[i]=sum_j P[i,j]V[j]; trans=1: O[m]=sum_n P[n,m]V[n]
__global__ void attn_pv_kernel(const float* __restrict__ S, const float* __restrict__ V,
                               const float* __restrict__ stm, const float* __restrict__ sts,
                               float* __restrict__ O, int trans) {
    int bh = blockIdx.y, b = bh / NHD, h = bh - b * NHD;
    int i0 = blockIdx.x * 32;
    int tid = threadIdx.x;
    int d = tid & 63, rg = tid >> 6;
    const float* Sb = S + (size_t)bh * NN * NN;
    const float* stmB = stm + (size_t)bh * NN + i0;
    const float* stsB = sts + (size_t)bh * NN + i0;
    __shared__ float Ps[32][33];
    __shared__ float Vs[32][65];
    float acc[8] = {0, 0, 0, 0, 0, 0, 0, 0};
    for (int j0 = 0; j0 < NN; j0 += 32) {
#pragma unroll
        for (int l = 0; l < 4; ++l) {
            int idx = tid + l * 256;
            if (!trans) {
                int ro = idx >> 5, jn = idx & 31;
                Ps[ro][jn] = expf(Sb[(size_t)(i0 + ro) * NN + j0 + jn] - stmB[ro]);
            } else {
                int ro = idx & 31, jn = idx >> 5;
                Ps[ro][jn] = expf(Sb[(size_t)(j0 + jn) * NN + i0 + ro] - stmB[ro]);
            }
        }
#pragma unroll
        for (int l = 0; l < 8; ++l) {
            int idx = tid + l * 256;
            int jn = idx >> 6, dd = idx & 63;
            Vs[jn][dd] = V[((size_t)b * NN + j0 + jn) * ND + h * 64 + dd];
        }
        __syncthreads();
#pragma unroll
        for (int jn = 0; jn < 32; ++jn) {
            float vv = Vs[jn][d];
#pragma unroll
            for (int k = 0; k < 8; ++k) acc[k] += Ps[rg * 8 + k][jn] * vv;
        }
        __syncthreads();
    }
#pragma unroll
    for (int k = 0; k < 8; ++k) {
        int ro = rg * 8 + k;
        O[((size_t)b * NN + i0 + ro) * ND + h * 64 + d] = acc[k] / stsB[ro];
    }
}

// ---------------- concat [x | m] -> [B*N, 512] ----------------
__global__ void concat2_kernel(const float* __restrict__ x, const float* __restrict__ m,
                               float* __restrict__ hc) {
    int idx = blockIdx.x * 256 + threadIdx.x;   // B*N*512
    int row = idx >> 9, c = idx & 511;
    hc[idx] = (c < 256) ? x[(size_t)row * 256 + c] : m[(size_t)row * 256 + c - 256];
}

// ---------------- LN (over 512) + exact GELU, in place ----------------
__global__ void ln_gelu_kernel(float* __restrict__ hbuf, const float* __restrict__ g,
                               const float* __restrict__ be) {
    __shared__ float sb[256];
    int row = blockIdx.x, tid = threadIdx.x;
    float* p = hbuf + (size_t)row * 512;
    float x0 = p[tid], x1 = p[tid + 256];
    sb[tid] = x0 + x1; __syncthreads();
    for (int s = 128; s > 0; s >>= 1) { if (tid < s) sb[tid] += sb[tid + s]; __syncthreads(); }
    float mu = sb[0] * (1.f / 512.f); __syncthreads();
    float d0 = x0 - mu, d1 = x1 - mu;
    sb[tid] = d0 * d0 + d1 * d1; __syncthreads();
    for (int s = 128; s > 0; s >>= 1) { if (tid < s) sb[tid] += sb[tid + s]; __syncthreads(); }
    float rstd = rsqrtf(sb[0] * (1.f / 512.f) + 1e-5f);
    float y0 = d0 * rstd * g[tid] + be[tid];
    float y1 = d1 * rstd * g[tid + 256] + be[tid + 256];
    p[tid]       = 0.5f * y0 * (1.f + erff(y0 * 0.70710678118654752f));
    p[tid + 256] = 0.5f * y1 * (1.f + erff(y1 * 0.70710678118654752f));
}

// ---------------- z = x @ Wm + bm  (one block per row) ----------------
__global__ void zproj_kernel(const float* __restrict__ X, const float* __restrict__ Wm,
                             const float* __restrict__ bm, float* __restrict__ z) {
    __shared__ float sb[256];
    int row = blockIdx.x, tid = threadIdx.x;
    float v = X[(size_t)row * 256 + tid] * Wm[tid];
    sb[tid] = v; __syncthreads();
    for (int s = 128; s > 0; s >>= 1) { if (tid < s) sb[tid] += sb[tid + s]; __syncthreads(); }
    if (tid == 0) z[row] = sb[0] + bm[0];
}

// ---------------- final assemble of [B, N+1, N+1] ----------------
__global__ void assemble_kernel(const float* __restrict__ sim2, const float* __restrict__ z0,
                                const float* __restrict__ z1, const float* __restrict__ rm,
                                const float* __restrict__ rs, const float* __restrict__ cm,
                                const float* __restrict__ cs, float* __restrict__ out) {
    int idx = blockIdx.x * 256 + threadIdx.x;
    if (idx >= NB * NP * NP) return;
    int b = idx / (NP * NP);
    int rem = idx - b * NP * NP;
    int i = rem / NP, j = rem - i * NP;
    float v;
    if (i < NN && j < NN) {
        float s = sim2[((size_t)b * NN + i) * NN + j];
        float lr = s - rm[b * NN + i] - logf(rs[b * NN + i]);
        float lc = s - cm[b * NN + j] - logf(cs[b * NN + j]);
        v = lr + lc + logsigf(z0[b * NN + i]) + logsigf(z1[b * NN + j]);
    } else if (i < NN) {
        v = logsigf(-z0[b * NN + i]);
    } else if (j < NN) {
        v = logsigf(-z1[b * NN + j]);
    } else {
        v = 0.f;
    }
    out[idx] = v;
}

extern "C" void kernel_launch(void* const* d_in, const int* in_sizes, int n_in,
                              void* d_out, int out_size, void* d_ws, size_t ws_size,
                              hipStream_t stream) {
    auto in = [&](int i) { return (const float*)d_in[i]; };
    const float* kpts0 = in(0);
    const float* kpts1 = in(1);
    const float* desc0 = in(2);
    const float* desc1 = in(3);
    const float* fx = in(4);
    const float* fy = in(5);
    const float* sWqk = in(6);  const float* sbqk = in(7);
    const float* sWv  = in(8);  const float* sbv  = in(9);
    const float* sWo  = in(10); const float* sbo  = in(11);
    const float* sW1  = in(12); const float* sb1  = in(13);
    const float* sg   = in(14); const float* sbe  = in(15);
    const float* sW2  = in(16); const float* sb2  = in(17);
    const float* cWqk = in(18); const float* cbqk = in(19);
    const float* cWv  = in(20); const float* cbv  = in(21);
    const float* cWo  = in(22); const float* cbo  = in(23);
    const float* cW1  = in(24); const float* cb1  = in(25);
    const float* cg   = in(26); const float* cbe  = in(27);
    const float* cW2  = in(28); const float* cb2  = in(29);
    const float* Wp = in(30); const float* bp = in(31);
    const float* Wm = in(32); const float* bm = in(33);

    const int Mrows = NB * NN;                 // 2048
    const size_t BND  = (size_t)Mrows * ND;    // 524288
    const size_t BN2D = (size_t)Mrows * 512;
    const size_t BNDH = (size_t)Mrows * 64;

    float* ws = (float*)d_ws;
    float* x0   = ws;             ws += BND;
    float* x1   = ws;             ws += BND;
    float* tA   = ws;             ws += BND;
    float* tB   = ws;             ws += BND;
    float* tC   = ws;             ws += BND;
    float* tD   = ws;             ws += BND;
    float* tM0  = ws;             ws += BND;
    float* tM1  = ws;             ws += BND;
    float* hcat = ws;             ws += BN2D;
    float* hbuf = ws;             ws += BN2D;
    float* cs0  = ws;             ws += BNDH;
    float* sn0  = ws;             ws += BNDH;
    float* cs1  = ws;             ws += BNDH;
    float* sn1  = ws;             ws += BNDH;
    float* Sbuf = ws;             ws += (size_t)NB * NHD * NN * NN;   // 33.5 MB
    float* sim2 = Sbuf;                                               // reuse in final phase
    float* z0   = ws;             ws += Mrows;
    float* z1   = ws;             ws += Mrows;
    float* st0  = ws;             ws += (size_t)NB * NHD * NN;
    float* st1  = ws;             ws += (size_t)NB * NHD * NN;
    float* st2  = ws;             ws += (size_t)NB * NHD * NN;
    float* st3  = ws;             ws += (size_t)NB * NHD * NN;

    auto gemm = [&](const float* A, const float* W, const float* b, const float* res, float* C,
                    int M, int K, int Nc, float scale) {
        gemm_kernel<<<dim3(Nc / 32, M / 32), dim3(16, 16), 0, stream>>>(A, W, b, res, C, M, K, Nc, scale);
    };

    // RoPE tables + init residual streams
    rope_cs_kernel<<<(Mrows * 64) / 256, 256, 0, stream>>>(kpts0, fx, fy, cs0, sn0);
    rope_cs_kernel<<<(Mrows * 64) / 256, 256, 0, stream>>>(kpts1, fx, fy, cs1, sn1);
    hipMemcpyAsync(x0, desc0, BND * sizeof(float), hipMemcpyDeviceToDevice, stream);
    hipMemcpyAsync(x1, desc1, BND * sizeof(float), hipMemcpyDeviceToDevice, stream);

    auto ffn = [&](float* x, const float* mo, const float* W1, const float* b1,
                   const float* g, const float* be, const float* W2, const float* b2) {
        concat2_kernel<<<(Mrows * 512) / 256, 256, 0, stream>>>(x, mo, hcat);
        gemm(hcat, W1, b1, nullptr, hbuf, Mrows, 512, 512, 1.f);
        ln_gelu_kernel<<<Mrows, 256, 0, stream>>>(hbuf, g, be);
        gemm(hbuf, W2, b2, x, x, Mrows, 512, 256, 1.f);
    };

    for (int i = 0; i < NL; ++i) {
        const size_t oDD = (size_t)i * ND * ND;       // 65536
        const size_t oW1 = (size_t)i * 512 * 512;
        const size_t oW2 = (size_t)i * 512 * 256;

        // ---- self blocks ----
        auto self_blk = [&](float* x, const float* csb, const float* snb) {
            gemm(x, sWqk + oDD, sbqk + i * ND, nullptr, tA, Mrows, 256, 256, 1.f);
            rope_apply_kernel<<<(Mrows * 128) / 256, 256, 0, stream>>>(tA, csb, snb);
            gemm(x, sWv + oDD, sbv + i * ND, nullptr, tC, Mrows, 256, 256, 1.f);
            scores_kernel<<<dim3(NN / 32, NN / 32, NB * NHD), dim3(16, 16), 0, stream>>>(
                tA, tA, Sbuf, NHD, 64, 0.125f);
            rowstats_kernel<<<NB * NHD * NN, 256, 0, stream>>>(Sbuf, st0, st1, NN);
            attn_pv_kernel<<<dim3(NN / 32, NB * NHD), 256, 0, stream>>>(Sbuf, tC, st0, st1, tM0, 0);
            gemm(tM0, sWo + oDD, sbo + i * ND, nullptr, tM1, Mrows, 256, 256, 1.f);
            ffn(x, tM1, sW1 + oW1, sb1 + i * 512, sg + i * 512, sbe + i * 512,
                sW2 + oW2, sb2 + i * ND);
        };
        self_blk(x0, cs0, sn0);
        self_blk(x1, cs1, sn1);

        // ---- cross block ----
        gemm(x0, cWqk + oDD, cbqk + i * ND, nullptr, tA, Mrows, 256, 256, 1.f);
        gemm(x1, cWqk + oDD, cbqk + i * ND, nullptr, tB, Mrows, 256, 256, 1.f);
        gemm(x0, cWv + oDD, cbv + i * ND, nullptr, tC, Mrows, 256, 256, 1.f);
        gemm(x1, cWv + oDD, cbv + i * ND, nullptr, tD, Mrows, 256, 256, 1.f);
        scores_kernel<<<dim3(NN / 32, NN / 32, NB * NHD), dim3(16, 16), 0, stream>>>(
            tA, tB, Sbuf, NHD, 64, 0.125f);
        rowstats_kernel<<<NB * NHD * NN, 256, 0, stream>>>(Sbuf, st0, st1, NN);
        colstats_kernel<<<dim3(NN / 256, NB * NHD), 256, 0, stream>>>(Sbuf, st2, st3, NN);
        attn_pv_kernel<<<dim3(NN / 32, NB * NHD), 256, 0, stream>>>(Sbuf, tD, st0, st1, tM0, 0);
        attn_pv_kernel<<<dim3(NN / 32, NB * NHD), 256, 0, stream>>>(Sbuf, tC, st2, st3, tM1, 1);
        gemm(tM0, cWo + oDD, cbo + i * ND, nullptr, tA, Mrows, 256, 256, 1.f);
        gemm(tM1, cWo + oDD, cbo + i * ND, nullptr, tB, Mrows, 256, 256, 1.f);
        ffn(x0, tA, cW1 + oW1, cb1 + i * 512, cg + i * 512, cbe + i * 512, cW2 + oW2, cb2 + i * ND);
        ffn(x1, tB, cW1 + oW1, cb1 + i * 512, cg + i * 512, cbe + i * 512, cW2 + oW2, cb2 + i * ND);
    }

    // ---- match head ----
    gemm(x0, Wp, bp, nullptr, tA, Mrows, 256, 256, 0.25f);   // md0 = (x0@Wp+bp)/D^0.25
    gemm(x1, Wp, bp, nullptr, tB, Mrows, 256, 256, 0.25f);   // md1
    zproj_kernel<<<Mrows, 256, 0, stream>>>(x0, Wm, bm, z0);
    zproj_kernel<<<Mrows, 256, 0, stream>>>(x1, Wm, bm, z1);
    scores_kernel<<<dim3(NN / 32, NN / 32, NB), dim3(16, 16), 0, stream>>>(tA, tB, sim2, 1, 256, 1.f);
    rowstats_kernel<<<NB * NN, 256, 0, stream>>>(sim2, st0, st1, NN);
    colstats_kernel<<<dim3(NN / 256, NB), 256, 0, stream>>>(sim2, st2, st3, NN);
    int total = NB * NP * NP;
    assemble_kernel<<<(total + 255) / 256, 256, 0, stream>>>(sim2, z0, z1, st0, st1, st2, st3,
                                                             (float*)d_out);
}

// Round 2
// 4494.758 us; speedup vs baseline: 1.9660x; 1.9660x over previous
//
#include <hip/hip_runtime.h>
#include <hip/hip_bf16.h>
#include <math.h>

#define NB 2
#define NN 1024
#define ND 256
#define NHD 4
#define NL 6
#define NP (NN + 1)

typedef unsigned short u16;
typedef __attribute__((ext_vector_type(8))) short bf16x8;
typedef __attribute__((ext_vector_type(4))) float f32x4;

__device__ __forceinline__ u16 f2b(float f) {
    union { float f; unsigned u; } v; v.f = f;
    unsigned r = v.u + 0x7FFFu + ((v.u >> 16) & 1u);
    return (u16)(r >> 16);
}

__device__ __forceinline__ float logsigf(float x) {
    return (x >= 0.f) ? -log1pf(expf(-x)) : (x - log1pf(expf(x)));
}

// ---------------- RoPE tables: cs/sn [B*N, 64] ----------------
__global__ void rope_cs_kernel(const float* __restrict__ kpts, const float* __restrict__ fx,
                               const float* __restrict__ fy, float* __restrict__ cs,
                               float* __restrict__ sn) {
    int idx = blockIdx.x * 256 + threadIdx.x;      // B*N*64
    int row = idx >> 6, j = idx & 63;
    float kx = kpts[row * 2], ky = kpts[row * 2 + 1];
    float f;
    if (j < 32) f = ((kx - 512.f) * (1.f / 512.f)) * fx[j >> 1];
    else        f = ((ky - 384.f) * (1.f / 512.f)) * fy[(j - 32) >> 1];
    cs[idx] = cosf(f);
    sn[idx] = sinf(f);
}

// ---------------- copy fp32 + bf16 mirror ----------------
__global__ void copyconv_kernel(const float* __restrict__ in, float* __restrict__ outf,
                                u16* __restrict__ outb, int n) {
    int i = blockIdx.x * 256 + threadIdx.x;
    if (i < n) { float v = in[i]; outf[i] = v; outb[i] = f2b(v); }
}

// ------- weight convert + transpose: in [Lz][K][N] f32 -> out [Lz][N][K] bf16 -------
__global__ void wconv_kernel(const float* __restrict__ in, u16* __restrict__ out, int K, int N) {
    __shared__ float t[32][33];
    int z = blockIdx.z;
    int k0 = blockIdx.y * 32, n0 = blockIdx.x * 32;
    const float* W = in + (size_t)z * K * N;
    u16* Wt = out + (size_t)z * K * N;
    int tx = threadIdx.x, ty = threadIdx.y;  // 32 x 8
    for (int i = 0; i < 32; i += 8)
        t[ty + i][tx] = W[(size_t)(k0 + ty + i) * N + n0 + tx];
    __syncthreads();
    for (int i = 0; i < 32; i += 8)
        Wt[(size_t)(n0 + ty + i) * K + k0 + tx] = f2b(t[tx][ty + i]);
}

// ---------------- rotary: read fp32 qk, write bf16 ----------------
__global__ void rope_apply_b(const float* __restrict__ qk, const float* __restrict__ cs,
                             const float* __restrict__ sn, u16* __restrict__ out) {
    int p = blockIdx.x * 256 + threadIdx.x;        // B*N*128 pairs
    int row = p >> 7;
    int d = (p & 127) * 2;
    int dh = d & 63;
    float c0 = cs[row * 64 + dh], c1 = cs[row * 64 + dh + 1];
    float s0 = sn[row * 64 + dh], s1 = sn[row * 64 + dh + 1];
    size_t base = (size_t)row * ND + d;
    float a = qk[base], b = qk[base + 1];
    out[base]     = f2b(a * c0 - b * s0);
    out[base + 1] = f2b(b * c1 + a * s1);
}

#define MFMA_BLOCK(As_, Bs_) do {                                              \
    bf16x8 a0 = *(bf16x8*)&As_[(wm + l15) * 40 + l4 * 8];                      \
    bf16x8 a1 = *(bf16x8*)&As_[(wm + 16 + l15) * 40 + l4 * 8];                 \
    bf16x8 b0 = *(bf16x8*)&Bs_[(wn + l15) * 40 + l4 * 8];                      \
    bf16x8 b1 = *(bf16x8*)&Bs_[(wn + 16 + l15) * 40 + l4 * 8];                 \
    acc[0][0] = __builtin_amdgcn_mfma_f32_16x16x32_bf16(a0, b0, acc[0][0], 0, 0, 0); \
    acc[0][1] = __builtin_amdgcn_mfma_f32_16x16x32_bf16(a0, b1, acc[0][1], 0, 0, 0); \
    acc[1][0] = __builtin_amdgcn_mfma_f32_16x16x32_bf16(a1, b0, acc[1][0], 0, 0, 0); \
    acc[1][1] = __builtin_amdgcn_mfma_f32_16x16x32_bf16(a1, b1, acc[1][1], 0, 0, 0); \
} while (0)

// ------- C = (A@B + bias)*scale + res; A bf16 [M][K], Bt bf16 [N][K]; Cf/Cb optional -------
__global__ void gemm_mfma(const u16* __restrict__ A, const u16* __restrict__ Bt,
                          const float* __restrict__ bias, const float* __restrict__ res,
                          float* __restrict__ Cf, u16* __restrict__ Cb,
                          int M, int N, int K, float scale) {
    __shared__ u16 As[64 * 40];
    __shared__ u16 Bs[64 * 40];
    int tid = threadIdx.x;
    int lane = tid & 63, wave = tid >> 6;
    int row0 = blockIdx.y * 64, col0 = blockIdx.x * 64;
    int wm = (wave >> 1) * 32, wn = (wave & 1) * 32;
    int l15 = lane & 15, l4 = lane >> 4;
    f32x4 acc[2][2] = {};
    int sr = tid >> 2, sc = (tid & 3) * 8;
    for (int k0 = 0; k0 < K; k0 += 32) {
        *(bf16x8*)&As[sr * 40 + sc] = *(const bf16x8*)&A[(size_t)(row0 + sr) * K + k0 + sc];
        *(bf16x8*)&Bs[sr * 40 + sc] = *(const bf16x8*)&Bt[(size_t)(col0 + sr) * K + k0 + sc];
        __syncthreads();
        MFMA_BLOCK(As, Bs);
        __syncthreads();
    }
#pragma unroll
    for (int mi = 0; mi < 2; ++mi)
#pragma unroll
        for (int ni = 0; ni < 2; ++ni)
#pragma unroll
            for (int j = 0; j < 4; ++j) {
                int r = row0 + wm + mi * 16 + l4 * 4 + j;
                int c = col0 + wn + ni * 16 + l15;
                float v = acc[mi][ni][j] + (bias ? bias[c] : 0.f);
                v *= scale;
                if (res) v += res[(size_t)r * N + c];
                if (Cf) Cf[(size_t)r * N + c] = v;
                if (Cb) Cb[(size_t)r * N + c] = f2b(v);
            }
}

// ------- S[z][i][j] = scale * sum_k Q[b][i][h*kd+k] * Kr[b][j][h*kd+k]; LD = row stride ----
__global__ void scores_mfma(const u16* __restrict__ Q, const u16* __restrict__ Kr,
                            float* __restrict__ S, int nh, int kd, int LD, float scale) {
    __shared__ u16 Qs[64 * 40];
    __shared__ u16 Ks[64 * 40];
    int z = blockIdx.z, b = z / nh, h = z - b * nh;
    const u16* Qb = Q + (size_t)b * NN * LD + h * kd;
    const u16* Kb = Kr + (size_t)b * NN * LD + h * kd;
    float* Sb = S + (size_t)z * NN * NN;
    int tid = threadIdx.x, lane = tid & 63, wave = tid >> 6;
    int i0 = blockIdx.y * 64, j0 = blockIdx.x * 64;
    int wm = (wave >> 1) * 32, wn = (wave & 1) * 32;
    int l15 = lane & 15, l4 = lane >> 4;
    f32x4 acc[2][2] = {};
    int sr = tid >> 2, sc = (tid & 3) * 8;
    for (int k0 = 0; k0 < kd; k0 += 32) {
        *(bf16x8*)&Qs[sr * 40 + sc] = *(const bf16x8*)&Qb[(size_t)(i0 + sr) * LD + k0 + sc];
        *(bf16x8*)&Ks[sr * 40 + sc] = *(const bf16x8*)&Kb[(size_t)(j0 + sr) * LD + k0 + sc];
        __syncthreads();
        MFMA_BLOCK(Qs, Ks);
        __syncthreads();
    }
#pragma unroll
    for (int mi = 0; mi < 2; ++mi)
#pragma unroll
        for (int ni = 0; ni < 2; ++ni)
#pragma unroll
            for (int j = 0; j < 4; ++j) {
                int r = i0 + wm + mi * 16 + l4 * 4 + j;
                int c = j0 + wn + ni * 16 + l15;
                Sb[(size_t)r * NN + c] = acc[mi][ni][j] * scale;
            }
}

// ------- PV with on-the-fly softmax, MFMA. TRANS=0: rows of S; TRANS=1: cols of S. -------
template <int TRANS>
__global__ void pv_mfma(const float* __restrict__ S, const u16* __restrict__ Vb,
                        const float* __restrict__ stm, const float* __restrict__ sts,
                        u16* __restrict__ Ob) {
    __shared__ u16 Ps[64 * 40];   // A tile: 64 out-rows x 32 k
    __shared__ u16 Vt[64 * 40];   // B tile: 64 d-cols x 32 k
    int bh = blockIdx.y, b = bh >> 2, h = bh & 3;
    int i0 = blockIdx.x * 64;
    const float* Sb = S + (size_t)bh * NN * NN;
    const float* m_ = stm + (size_t)bh * NN;
    const float* s_ = sts + (size_t)bh * NN;
    int tid = threadIdx.x, lane = tid & 63, wave = tid >> 6;
    int wm = (wave >> 1) * 32, wn = (wave & 1) * 32;
    int l15 = lane & 15, l4 = lane >> 4;
    f32x4 acc[2][2] = {};
    for (int j0 = 0; j0 < NN; j0 += 32) {
        if (TRANS == 0) {
            int r = tid >> 2, c0 = (tid & 3) * 8;
            float mm = m_[i0 + r];
            const float* src = &Sb[(size_t)(i0 + r) * NN + j0 + c0];
            u16* dst = &Ps[r * 40 + c0];
#pragma unroll
            for (int q = 0; q < 8; ++q) dst[q] = f2b(__expf(src[q] - mm));
        } else {
            int n = tid >> 3, c0 = (tid & 7) * 8;
            const float* src = &Sb[(size_t)(j0 + n) * NN + i0 + c0];
#pragma unroll
            for (int q = 0; q < 8; ++q) Ps[(c0 + q) * 40 + n] = f2b(__expf(src[q] - m_[i0 + c0 + q]));
        }
        {
            int jj = tid >> 3, d0 = (tid & 7) * 8;
            bf16x8 v = *(const bf16x8*)&Vb[((size_t)b * NN + j0 + jj) * ND + h * 64 + d0];
#pragma unroll
            for (int q = 0; q < 8; ++q) Vt[(d0 + q) * 40 + jj] = ((u16*)&v)[q];
        }
        __syncthreads();
        MFMA_BLOCK(Ps, Vt);
        __syncthreads();
    }
#pragma unroll
    for (int mi = 0; mi < 2; ++mi)
#pragma unroll
        for (int ni = 0; ni < 2; ++ni)
#pragma unroll
            for (int j = 0; j < 4; ++j) {
                int r = i0 + wm + mi * 16 + l4 * 4 + j;
                int d = wn + ni * 16 + l15;
                float v = acc[mi][ni][j] / s_[r];
                Ob[((size_t)b * NN + r) * ND + h * 64 + d] = f2b(v);
            }
}

// ---------------- per-row max & sumexp ----------------
__global__ void rowstats_kernel(const float* __restrict__ S, float* __restrict__ rm,
                                float* __restrict__ rs, int ncols) {
    __shared__ float sb[256];
    int row = blockIdx.x, tid = threadIdx.x;
    const float* p = S + (size_t)row * ncols;
    float m = -1e30f;
    for (int j = tid; j < ncols; j += 256) m = fmaxf(m, p[j]);
    sb[tid] = m; __syncthreads();
    for (int s = 128; s > 0; s >>= 1) { if (tid < s) sb[tid] = fmaxf(sb[tid], sb[tid + s]); __syncthreads(); }
    m = sb[0]; __syncthreads();
    float s = 0;
    for (int j = tid; j < ncols; j += 256) s += __expf(p[j] - m);
    sb[tid] = s; __syncthreads();
    for (int st = 128; st > 0; st >>= 1) { if (tid < st) sb[tid] += sb[tid + st]; __syncthreads(); }
    if (tid == 0) { rm[row] = m; rs[row] = sb[0]; }
}

// ---------------- per-col max & sumexp ----------------
__global__ void colstats_kernel(const float* __restrict__ S, float* __restrict__ cm,
                                float* __restrict__ cs, int nrows) {
    int mat = blockIdx.y;
    int j = blockIdx.x * 256 + threadIdx.x;
    const float* p = S + (size_t)mat * nrows * NN + j;
    float m = -1e30f;
    for (int i = 0; i < nrows; ++i) m = fmaxf(m, p[(size_t)i * NN]);
    float s = 0;
    for (int i = 0; i < nrows; ++i) s += __expf(p[(size_t)i * NN] - m);
    cm[(size_t)mat * NN + j] = m;
    cs[(size_t)mat * NN + j] = s;
}

// ---------------- concat [x | m] -> bf16 [B*N, 512] ----------------
__global__ void concat2_b(const float* __restrict__ x, const float* __restrict__ m,
                          u16* __restrict__ hc) {
    int idx = blockIdx.x * 256 + threadIdx.x;   // B*N*512
    int row = idx >> 9, c = idx & 511;
    float v = (c < 256) ? x[(size_t)row * 256 + c] : m[(size_t)row * 256 + c - 256];
    hc[idx] = f2b(v);
}

// ---------------- LN (over 512) + exact GELU: fp32 in, bf16 out ----------------
__global__ void ln_gelu_b(const float* __restrict__ hbuf, const float* __restrict__ g,
                          const float* __restrict__ be, u16* __restrict__ out) {
    __shared__ float sb[256];
    int row = blockIdx.x, tid = threadIdx.x;
    const float* p = hbuf + (size_t)row * 512;
    float x0 = p[tid], x1 = p[tid + 256];
    sb[tid] = x0 + x1; __syncthreads();
    for (int s = 128; s > 0; s >>= 1) { if (tid < s) sb[tid] += sb[tid + s]; __syncthreads(); }
    float mu = sb[0] * (1.f / 512.f); __syncthreads();
    float d0 = x0 - mu, d1 = x1 - mu;
    sb[tid] = d0 * d0 + d1 * d1; __syncthreads();
    for (int s = 128; s > 0; s >>= 1) { if (tid < s) sb[tid] += sb[tid + s]; __syncthreads(); }
    float rstd = rsqrtf(sb[0] * (1.f / 512.f) + 1e-5f);
    float y0 = d0 * rstd * g[tid] + be[tid];
    float y1 = d1 * rstd * g[tid + 256] + be[tid + 256];
    out[(size_t)row * 512 + tid]       = f2b(0.5f * y0 * (1.f + erff(y0 * 0.70710678118654752f)));
    out[(size_t)row * 512 + tid + 256] = f2b(0.5f * y1 * (1.f + erff(y1 * 0.70710678118654752f)));
}

// ---------------- z = x @ Wm + bm ----------------
__global__ void zproj_kernel(const float* __restrict__ X, const float* __restrict__ Wm,
                             const float* __restrict__ bm, float* __restrict__ z) {
    __shared__ float sb[256];
    int row = blockIdx.x, tid = threadIdx.x;
    float v = X[(size_t)row * 256 + tid] * Wm[tid];
    sb[tid] = v; __syncthreads();
    for (int s = 128; s > 0; s >>= 1) { if (tid < s) sb[tid] += sb[tid + s]; __syncthreads(); }
    if (tid == 0) z[row] = sb[0] + bm[0];
}

// ---------------- final assemble of [B, N+1, N+1] ----------------
__global__ void assemble_kernel(const float* __restrict__ sim2, const float* __restrict__ z0,
                                const float* __restrict__ z1, const float* __restrict__ rm,
                                const float* __restrict__ rs, const float* __restrict__ cm,
                                const float* __restrict__ cs, float* __restrict__ out) {
    int idx = blockIdx.x * 256 + threadIdx.x;
    if (idx >= NB * NP * NP) return;
    int b = idx / (NP * NP);
    int rem = idx - b * NP * NP;
    int i = rem / NP, j = rem - i * NP;
    float v;
    if (i < NN && j < NN) {
        float s = sim2[((size_t)b * NN + i) * NN + j];
        float lr = s - rm[b * NN + i] - logf(rs[b * NN + i]);
        float lc = s - cm[b * NN + j] - logf(cs[b * NN + j]);
        v = lr + lc + logsigf(z0[b * NN + i]) + logsigf(z1[b * NN + j]);
    } else if (i < NN) {
        v = logsigf(-z0[b * NN + i]);
    } else if (j < NN) {
        v = logsigf(-z1[b * NN + j]);
    } else {
        v = 0.f;
    }
    out[idx] = v;
}

extern "C" void kernel_launch(void* const* d_in, const int* in_sizes, int n_in,
                              void* d_out, int out_size, void* d_ws, size_t ws_size,
                              hipStream_t stream) {
    auto in = [&](int i) { return (const float*)d_in[i]; };
    const float* kpts0 = in(0);
    const float* kpts1 = in(1);
    const float* desc0 = in(2);
    const float* desc1 = in(3);
    const float* fx = in(4);
    const float* fy = in(5);
    const float* sWqk = in(6);  const float* sbqk = in(7);
    const float* sWv  = in(8);  const float* sbv  = in(9);
    const float* sWo  = in(10); const float* sbo  = in(11);
    const float* sW1  = in(12); const float* sb1  = in(13);
    const float* sg   = in(14); const float* sbe  = in(15);
    const float* sW2  = in(16); const float* sb2  = in(17);
    const float* cWqk = in(18); const float* cbqk = in(19);
    const float* cWv  = in(20); const float* cbv  = in(21);
    const float* cWo  = in(22); const float* cbo  = in(23);
    const float* cW1  = in(24); const float* cb1  = in(25);
    const float* cg   = in(26); const float* cbe  = in(27);
    const float* cW2  = in(28); const float* cb2  = in(29);
    const float* Wp = in(30); const float* bp = in(31);
    const float* Wm = in(32); const float* bm = in(33);

    const int Mrows = NB * NN;                 // 2048
    const size_t BND = (size_t)Mrows * ND;     // 524288

    char* base = (char*)d_ws;
    size_t off = 0;
    auto allocf = [&](size_t n) { float* p = (float*)(base + off); off += ((n * 4 + 255) & ~(size_t)255); return p; };
    auto allocb = [&](size_t n) { u16* p = (u16*)(base + off);   off += ((n * 2 + 255) & ~(size_t)255); return p; };

    float* x0   = allocf(BND);
    float* x1   = allocf(BND);
    float* tA   = allocf(BND);
    float* tB   = allocf(BND);
    float* hbuf = allocf((size_t)Mrows * 512);
    float* cs0  = allocf((size_t)Mrows * 64);
    float* sn0  = allocf((size_t)Mrows * 64);
    float* cs1  = allocf((size_t)Mrows * 64);
    float* sn1  = allocf((size_t)Mrows * 64);
    float* Sbuf = allocf((size_t)NB * NHD * NN * NN);   // 33.5 MB
    float* sim2 = Sbuf;
    float* z0   = allocf(Mrows);
    float* z1   = allocf(Mrows);
    float* st0  = allocf((size_t)NB * NHD * NN);
    float* st1  = allocf((size_t)NB * NHD * NN);
    float* st2  = allocf((size_t)NB * NHD * NN);
    float* st3  = allocf((size_t)NB * NHD * NN);

    u16* x0b   = allocb(BND);
    u16* x1b   = allocb(BND);
    u16* tAb   = allocb(BND);
    u16* tBb   = allocb(BND);
    u16* tCb   = allocb(BND);
    u16* tDb   = allocb(BND);
    u16* tM0b  = allocb(BND);
    u16* hcatb = allocb((size_t)Mrows * 512);
    u16* hgelb = allocb((size_t)Mrows * 512);
    u16* wsqk = allocb((size_t)NL * 256 * 256);
    u16* wsv  = allocb((size_t)NL * 256 * 256);
    u16* wso  = allocb((size_t)NL * 256 * 256);
    u16* wsw1 = allocb((size_t)NL * 512 * 512);
    u16* wsw2 = allocb((size_t)NL * 512 * 256);
    u16* wcqk = allocb((size_t)NL * 256 * 256);
    u16* wcv  = allocb((size_t)NL * 256 * 256);
    u16* wco  = allocb((size_t)NL * 256 * 256);
    u16* wcw1 = allocb((size_t)NL * 512 * 512);
    u16* wcw2 = allocb((size_t)NL * 512 * 256);
    u16* wpb  = allocb((size_t)256 * 256);

    // ---- weight conversion (per call; graph-safe) ----
    auto wconv = [&](const float* w, u16* wt, int K, int N, int Lz) {
        wconv_kernel<<<dim3(N / 32, K / 32, Lz), dim3(32, 8), 0, stream>>>(w, wt, K, N);
    };
    wconv(sWqk, wsqk, 256, 256, NL); wconv(sWv, wsv, 256, 256, NL); wconv(sWo, wso, 256, 256, NL);
    wconv(sW1, wsw1, 512, 512, NL);  wconv(sW2, wsw2, 512, 256, NL);
    wconv(cWqk, wcqk, 256, 256, NL); wconv(cWv, wcv, 256, 256, NL); wconv(cWo, wco, 256, 256, NL);
    wconv(cW1, wcw1, 512, 512, NL);  wconv(cW2, wcw2, 512, 256, NL);
    wconv(Wp, wpb, 256, 256, 1);

    rope_cs_kernel<<<(Mrows * 64) / 256, 256, 0, stream>>>(kpts0, fx, fy, cs0, sn0);
    rope_cs_kernel<<<(Mrows * 64) / 256, 256, 0, stream>>>(kpts1, fx, fy, cs1, sn1);
    copyconv_kernel<<<(int)(BND / 256), 256, 0, stream>>>(desc0, x0, x0b, (int)BND);
    copyconv_kernel<<<(int)(BND / 256), 256, 0, stream>>>(desc1, x1, x1b, (int)BND);

    auto gemm = [&](const u16* A, const u16* Bt, const float* bias, const float* res,
                    float* Cf, u16* Cb, int M, int N, int K, float scale) {
        gemm_mfma<<<dim3(N / 64, M / 64), 256, 0, stream>>>(A, Bt, bias, res, Cf, Cb, M, N, K, scale);
    };

    auto ffn = [&](float* x, u16* xb, const float* mo, const u16* W1t, const float* b1,
                   const float* g, const float* be, const u16* W2t, const float* b2) {
        concat2_b<<<(Mrows * 512) / 256, 256, 0, stream>>>(x, mo, hcatb);
        gemm(hcatb, W1t, b1, nullptr, hbuf, nullptr, Mrows, 512, 512, 1.f);
        ln_gelu_b<<<Mrows, 256, 0, stream>>>(hbuf, g, be, hgelb);
        gemm(hgelb, W2t, b2, x, x, xb, Mrows, 256, 512, 1.f);
    };

    const float sc = 0.35355339059327379f;   // DH^-0.25

    for (int i = 0; i < NL; ++i) {
        const size_t oDD = (size_t)i * 256 * 256;
        const size_t oW1 = (size_t)i * 512 * 512;
        const size_t oW2 = (size_t)i * 512 * 256;

        // ---- self blocks ----
        auto self_blk = [&](float* x, u16* xb, const float* csb, const float* snb) {
            gemm(xb, wsqk + oDD, sbqk + i * ND, nullptr, tA, nullptr, Mrows, 256, 256, 1.f);
            rope_apply_b<<<(Mrows * 128) / 256, 256, 0, stream>>>(tA, csb, snb, tAb);
            gemm(xb, wsv + oDD, sbv + i * ND, nullptr, nullptr, tCb, Mrows, 256, 256, 1.f);
            scores_mfma<<<dim3(16, 16, NB * NHD), 256, 0, stream>>>(tAb, tAb, Sbuf, NHD, 64, ND, 0.125f);
            rowstats_kernel<<<NB * NHD * NN, 256, 0, stream>>>(Sbuf, st0, st1, NN);
            pv_mfma<0><<<dim3(16, NB * NHD), 256, 0, stream>>>(Sbuf, tCb, st0, st1, tM0b);
            gemm(tM0b, wso + oDD, sbo + i * ND, nullptr, tB, nullptr, Mrows, 256, 256, 1.f);
            ffn(x, xb, tB, wsw1 + oW1, sb1 + i * 512, sg + i * 512, sbe + i * 512,
                wsw2 + oW2, sb2 + i * ND);
        };
        self_blk(x0, x0b, cs0, sn0);
        self_blk(x1, x1b, cs1, sn1);

        // ---- cross block ----
        gemm(x0b, wcqk + oDD, cbqk + i * ND, nullptr, nullptr, tAb, Mrows, 256, 256, sc);
        gemm(x1b, wcqk + oDD, cbqk + i * ND, nullptr, nullptr, tBb, Mrows, 256, 256, sc);
        gemm(x0b, wcv + oDD, cbv + i * ND, nullptr, nullptr, tCb, Mrows, 256, 256, 1.f);
        gemm(x1b, wcv + oDD, cbv + i * ND, nullptr, nullptr, tDb, Mrows, 256, 256, 1.f);
        scores_mfma<<<dim3(16, 16, NB * NHD), 256, 0, stream>>>(tAb, tBb, Sbuf, NHD, 64, ND, 1.f);
        rowstats_kernel<<<NB * NHD * NN, 256, 0, stream>>>(Sbuf, st0, st1, NN);
        colstats_kernel<<<dim3(NN / 256, NB * NHD), 256, 0, stream>>>(Sbuf, st2, st3, NN);
        pv_mfma<0><<<dim3(16, NB * NHD), 256, 0, stream>>>(Sbuf, tDb, st0, st1, tM0b);
        gemm(tM0b, wco + oDD, cbo + i * ND, nullptr, tA, nullptr, Mrows, 256, 256, 1.f);
        pv_mfma<1><<<dim3(16, NB * NHD), 256, 0, stream>>>(Sbuf, tCb, st2, st3, tM0b);
        gemm(tM0b, wco + oDD, cbo + i * ND, nullptr, tB, nullptr, Mrows, 256, 256, 1.f);
        ffn(x0, x0b, tA, wcw1 + oW1, cb1 + i * 512, cg + i * 512, cbe + i * 512, wcw2 + oW2, cb2 + i * ND);
        ffn(x1, x1b, tB, wcw1 + oW1, cb1 + i * 512, cg + i * 512, cbe + i * 512, wcw2 + oW2, cb2 + i * ND);
    }

    // ---- match head ----
    gemm(x0b, wpb, bp, nullptr, nullptr, tAb, Mrows, 256, 256, 0.25f);   // md0
    gemm(x1b, wpb, bp, nullptr, nullptr, tBb, Mrows, 256, 256, 0.25f);   // md1
    zproj_kernel<<<Mrows, 256, 0, stream>>>(x0, Wm, bm, z0);
    zproj_kernel<<<Mrows, 256, 0, stream>>>(x1, Wm, bm, z1);
    scores_mfma<<<dim3(16, 16, NB), 256, 0, stream>>>(tAb, tBb, sim2, 1, 256, 256, 1.f);
    rowstats_kernel<<<NB * NN, 256, 0, stream>>>(sim2, st0, st1, NN);
    colstats_kernel<<<dim3(NN / 256, NB), 256, 0, stream>>>(sim2, st2, st3, NN);
    int total = NB * NP * NP;
    assemble_kernel<<<(total + 255) / 256, 256, 0, stream>>>(sim2, z0, z1, st0, st1, st2, st3,
                                                             (float*)d_out);
}

// Round 3
// 1786.308 us; speedup vs baseline: 4.9469x; 2.5162x over previous
//
#include <hip/hip_runtime.h>
#include <hip/hip_bf16.h>
#include <math.h>

#define NB 2
#define NN 1024
#define ND 256
#define NHD 4
#define NL 6
#define NP (NN + 1)

typedef unsigned short u16;
typedef __attribute__((ext_vector_type(8))) short bf16x8;
typedef __attribute__((ext_vector_type(4))) float f32x4;

__device__ __forceinline__ u16 f2b(float f) {
    union { float f; unsigned u; } v; v.f = f;
    unsigned r = v.u + 0x7FFFu + ((v.u >> 16) & 1u);
    return (u16)(r >> 16);
}
__device__ __forceinline__ float b2f(u16 b) {
    union { unsigned u; float f; } v; v.u = ((unsigned)b) << 16;
    return v.f;
}
__device__ __forceinline__ float logsigf(float x) {
    return (x >= 0.f) ? -log1pf(expf(-x)) : (x - log1pf(expf(x)));
}

// ---------------- RoPE tables: cs/sn rows [2048,64] written at out offset ----------------
__global__ void rope_cs_kernel(const float* __restrict__ kpts, const float* __restrict__ fx,
                               const float* __restrict__ fy, float* __restrict__ cs,
                               float* __restrict__ sn) {
    int idx = blockIdx.x * 256 + threadIdx.x;      // 2048*64
    int row = idx >> 6, j = idx & 63;
    float kx = kpts[row * 2], ky = kpts[row * 2 + 1];
    float f;
    if (j < 32) f = ((kx - 512.f) * (1.f / 512.f)) * fx[j >> 1];
    else        f = ((ky - 384.f) * (1.f / 512.f)) * fy[(j - 32) >> 1];
    cs[idx] = cosf(f);
    sn[idx] = sinf(f);
}

// ---------------- copy fp32 + bf16 mirror ----------------
__global__ void copyconv_kernel(const float* __restrict__ in, float* __restrict__ outf,
                                u16* __restrict__ outb, int n) {
    int i = blockIdx.x * 256 + threadIdx.x;
    if (i < n) { float v = in[i]; outf[i] = v; outb[i] = f2b(v); }
}

// ------- weight convert + transpose: in [Lz][K][N] f32 -> out [Lz-stride outZ][N][K] bf16 ----
__global__ void wconv_kernel(const float* __restrict__ in, u16* __restrict__ out, int K, int N,
                             size_t outZ) {
    __shared__ float t[32][33];
    int z = blockIdx.z;
    int k0 = blockIdx.y * 32, n0 = blockIdx.x * 32;
    const float* W = in + (size_t)z * K * N;
    u16* Wt = out + (size_t)z * outZ;
    int tx = threadIdx.x, ty = threadIdx.y;  // 32 x 8
    for (int i = 0; i < 32; i += 8)
        t[ty + i][tx] = W[(size_t)(k0 + ty + i) * N + n0 + tx];
    __syncthreads();
    for (int i = 0; i < 32; i += 8)
        Wt[(size_t)(n0 + ty + i) * K + k0 + tx] = f2b(t[tx][ty + i]);
}

// ---------------- pack [L][256]+[L][256] biases -> [L][512] ----------------
__global__ void biaspack_kernel(const float* __restrict__ b0, const float* __restrict__ b1,
                                float* __restrict__ out, int L) {
    int idx = blockIdx.x * 256 + threadIdx.x;
    if (idx >= L * 512) return;
    int i = idx >> 9, c = idx & 511;
    out[idx] = (c < 256) ? b0[i * 256 + c] : b1[i * 256 + c - 256];
}

#define MFMA_BLOCK(As_, Bs_) do {                                              \
    bf16x8 a0 = *(bf16x8*)&As_[(wm + l15) * 40 + l4 * 8];                      \
    bf16x8 a1 = *(bf16x8*)&As_[(wm + 16 + l15) * 40 + l4 * 8];                 \
    bf16x8 b0 = *(bf16x8*)&Bs_[(wn + l15) * 40 + l4 * 8];                      \
    bf16x8 b1 = *(bf16x8*)&Bs_[(wn + 16 + l15) * 40 + l4 * 8];                 \
    acc[0][0] = __builtin_amdgcn_mfma_f32_16x16x32_bf16(a0, b0, acc[0][0], 0, 0, 0); \
    acc[0][1] = __builtin_amdgcn_mfma_f32_16x16x32_bf16(a0, b1, acc[0][1], 0, 0, 0); \
    acc[1][0] = __builtin_amdgcn_mfma_f32_16x16x32_bf16(a1, b0, acc[1][0], 0, 0, 0); \
    acc[1][1] = __builtin_amdgcn_mfma_f32_16x16x32_bf16(a1, b1, acc[1][1], 0, 0, 0); \
} while (0)

// ------- C = rope?((A@B + bias))*scale + res; A bf16 [M][K] (A2: concat halves of 256),
//         Bt bf16 [N][K]; optional fused rope on cols<256 (csp/snp [M][64]) -------
__global__ __launch_bounds__(256)
void gemm_mfma(const u16* __restrict__ A, const u16* __restrict__ A2,
               const u16* __restrict__ Bt, const float* __restrict__ bias,
               const float* __restrict__ res, float* __restrict__ Cf, u16* __restrict__ Cb,
               int M, int N, int K, float scale,
               const float* __restrict__ csp, const float* __restrict__ snp) {
    __shared__ u16 As[64 * 40];
    __shared__ u16 Bs[64 * 40];
    int tid = threadIdx.x;
    int lane = tid & 63, wave = tid >> 6;
    int row0 = blockIdx.y * 64, col0 = blockIdx.x * 64;
    int wm = (wave >> 1) * 32, wn = (wave & 1) * 32;
    int l15 = lane & 15, l4 = lane >> 4;
    f32x4 acc[2][2] = {};
    int sr = tid >> 2, sc = (tid & 3) * 8;
    for (int k0 = 0; k0 < K; k0 += 32) {
        const u16* asrc;
        if (A2) {
            int kg = k0 + sc;
            asrc = (kg < 256) ? &A[(size_t)(row0 + sr) * 256 + kg]
                              : &A2[(size_t)(row0 + sr) * 256 + kg - 256];
        } else {
            asrc = &A[(size_t)(row0 + sr) * K + k0 + sc];
        }
        *(bf16x8*)&As[sr * 40 + sc] = *(const bf16x8*)asrc;
        *(bf16x8*)&Bs[sr * 40 + sc] = *(const bf16x8*)&Bt[(size_t)(col0 + sr) * K + k0 + sc];
        __syncthreads();
        MFMA_BLOCK(As, Bs);
        __syncthreads();
    }
#pragma unroll
    for (int mi = 0; mi < 2; ++mi)
#pragma unroll
        for (int ni = 0; ni < 2; ++ni)
#pragma unroll
            for (int j = 0; j < 4; ++j) {
                int r = row0 + wm + mi * 16 + l4 * 4 + j;
                int c = col0 + wn + ni * 16 + l15;
                float v = acc[mi][ni][j] + (bias ? bias[c] : 0.f);
                float pn = __shfl_xor(v, 1);    // partner column (c^1), same row
                if (csp && c < 256) {
                    float cc = csp[(size_t)r * 64 + (c & 63)];
                    float ss = snp[(size_t)r * 64 + (c & 63)];
                    v = (c & 1) ? (v * cc + pn * ss) : (v * cc - pn * ss);
                }
                v *= scale;
                if (res) v += res[(size_t)r * N + c];
                if (Cf) Cf[(size_t)r * N + c] = v;
                if (Cb) Cb[(size_t)r * N + c] = f2b(v);
            }
}

// ------- flash attention: rows of O = softmax(Q K^T * scale) V.
// Q/K from Qp (stride ldq, head col h*64), V from Vp (stride ldv), O to Ob (stride 256).
// grid: x = q-tile (16), y = t*8+b*4+h (16). kswap: K/V come from the other tensor. -------
__global__ __launch_bounds__(256)
void flash_kernel(const u16* __restrict__ Qp, int ldq,
                  const u16* __restrict__ Vp, int ldv,
                  u16* __restrict__ Ob, float scale, int kswap) {
    __shared__ u16 Qs[64 * 72];
    __shared__ u16 Ks[64 * 72];
    __shared__ u16 Vt[64 * 72];
    __shared__ u16 Ps[64 * 72];
    int y = blockIdx.y;
    int t = y >> 3, b = (y >> 2) & 1, h = y & 3;
    int qR = t * 2048 + b * 1024;
    int kt = kswap ? (1 - t) : t;
    int kR = kt * 2048 + b * 1024;
    int i0 = blockIdx.x * 64;
    int tid = threadIdx.x, lane = tid & 63, wave = tid >> 6;
    int l15 = lane & 15, l4 = lane >> 4;
    int wm = wave * 16;                      // this wave's q band
    // stage Q once
#pragma unroll
    for (int it = 0; it < 2; ++it) {
        int idx = tid + it * 256;
        int r = idx >> 3, ch = (idx & 7) * 8;
        *(bf16x8*)&Qs[r * 72 + ch] =
            *(const bf16x8*)&Qp[(size_t)(qR + i0 + r) * ldq + h * 64 + ch];
    }
    float m[4], l[4];
    f32x4 accO[4] = {};
#pragma unroll
    for (int j = 0; j < 4; ++j) { m[j] = -1e30f; l[j] = 0.f; }

    for (int j0 = 0; j0 < NN; j0 += 64) {
#pragma unroll
        for (int it = 0; it < 2; ++it) {
            int idx = tid + it * 256;
            int r = idx >> 3, ch = (idx & 7) * 8;
            *(bf16x8*)&Ks[r * 72 + ch] =
                *(const bf16x8*)&Qp[(size_t)(kR + j0 + r) * ldq + h * 64 + ch];
        }
#pragma unroll
        for (int it = 0; it < 2; ++it) {
            int idx = tid + it * 256;
            int jj = idx >> 3, d0 = (idx & 7) * 8;
            bf16x8 v = *(const bf16x8*)&Vp[(size_t)(kR + j0 + jj) * ldv + h * 64 + d0];
#pragma unroll
            for (int q = 0; q < 8; ++q) Vt[(d0 + q) * 72 + jj] = ((u16*)&v)[q];
        }
        __syncthreads();
        // S tile (16 q x 64 kk) for this wave
        f32x4 accS[4] = {};
#pragma unroll
        for (int ks = 0; ks < 2; ++ks) {
            bf16x8 a = *(bf16x8*)&Qs[(wm + l15) * 72 + ks * 32 + l4 * 8];
#pragma unroll
            for (int n = 0; n < 4; ++n) {
                bf16x8 bb = *(bf16x8*)&Ks[(n * 16 + l15) * 72 + ks * 32 + l4 * 8];
                accS[n] = __builtin_amdgcn_mfma_f32_16x16x32_bf16(a, bb, accS[n], 0, 0, 0);
            }
        }
        // online softmax per row (row = wm + l4*4 + j)
        float p[4][4];
#pragma unroll
        for (int j = 0; j < 4; ++j) {
            float tm = fmaxf(fmaxf(accS[0][j], accS[1][j]), fmaxf(accS[2][j], accS[3][j])) * scale;
#pragma unroll
            for (int d = 1; d < 16; d <<= 1) tm = fmaxf(tm, __shfl_xor(tm, d));
            float mnew = fmaxf(m[j], tm);
            float r = __expf(m[j] - mnew);
            float ts = 0.f;
#pragma unroll
            for (int n = 0; n < 4; ++n) {
                float pv = __expf(accS[n][j] * scale - mnew);
                p[n][j] = pv; ts += pv;
            }
#pragma unroll
            for (int d = 1; d < 16; d <<= 1) ts += __shfl_xor(ts, d);
            l[j] = l[j] * r + ts;
            m[j] = mnew;
#pragma unroll
            for (int n = 0; n < 4; ++n) accO[n][j] *= r;
        }
        // write P (own band only) then PV
#pragma unroll
        for (int j = 0; j < 4; ++j)
#pragma unroll
            for (int n = 0; n < 4; ++n)
                Ps[(wm + l4 * 4 + j) * 72 + n * 16 + l15] = f2b(p[n][j]);
#pragma unroll
        for (int ks = 0; ks < 2; ++ks) {
            bf16x8 a = *(bf16x8*)&Ps[(wm + l15) * 72 + ks * 32 + l4 * 8];
#pragma unroll
            for (int n = 0; n < 4; ++n) {
                bf16x8 bb = *(bf16x8*)&Vt[(n * 16 + l15) * 72 + ks * 32 + l4 * 8];
                accO[n] = __builtin_amdgcn_mfma_f32_16x16x32_bf16(a, bb, accO[n], 0, 0, 0);
            }
        }
        __syncthreads();
    }
#pragma unroll
    for (int n = 0; n < 4; ++n)
#pragma unroll
        for (int j = 0; j < 4; ++j) {
            int r = i0 + wm + l4 * 4 + j;
            int d = n * 16 + l15;
            Ob[(size_t)(qR + r) * ND + h * 64 + d] = f2b(accO[n][j] / l[j]);
        }
}

// ------- S[z][i][j] = scale * sum_k Q[z-batch rows] (for final sim) -------
__global__ void scores_mfma(const u16* __restrict__ Q, const u16* __restrict__ Kr,
                            float* __restrict__ S, int nh, int kd, int LD, float scale) {
    __shared__ u16 Qs[64 * 40];
    __shared__ u16 Ks[64 * 40];
    int z = blockIdx.z, b = z / nh, h = z - b * nh;
    const u16* Qb = Q + (size_t)b * NN * LD + h * kd;
    const u16* Kb = Kr + (size_t)b * NN * LD + h * kd;
    float* Sb = S + (size_t)z * NN * NN;
    int tid = threadIdx.x, lane = tid & 63, wave = tid >> 6;
    int i0 = blockIdx.y * 64, j0 = blockIdx.x * 64;
    int wm = (wave >> 1) * 32, wn = (wave & 1) * 32;
    int l15 = lane & 15, l4 = lane >> 4;
    f32x4 acc[2][2] = {};
    int sr = tid >> 2, sc = (tid & 3) * 8;
    for (int k0 = 0; k0 < kd; k0 += 32) {
        *(bf16x8*)&Qs[sr * 40 + sc] = *(const bf16x8*)&Qb[(size_t)(i0 + sr) * LD + k0 + sc];
        *(bf16x8*)&Ks[sr * 40 + sc] = *(const bf16x8*)&Kb[(size_t)(j0 + sr) * LD + k0 + sc];
        __syncthreads();
        MFMA_BLOCK(Qs, Ks);
        __syncthreads();
    }
#pragma unroll
    for (int mi = 0; mi < 2; ++mi)
#pragma unroll
        for (int ni = 0; ni < 2; ++ni)
#pragma unroll
            for (int j = 0; j < 4; ++j) {
                int r = i0 + wm + mi * 16 + l4 * 4 + j;
                int c = j0 + wn + ni * 16 + l15;
                Sb[(size_t)r * NN + c] = acc[mi][ni][j] * scale;
            }
}

// ---------------- per-row max & sumexp ----------------
__global__ void rowstats_kernel(const float* __restrict__ S, float* __restrict__ rm,
                                float* __restrict__ rs, int ncols) {
    __shared__ float sb[256];
    int row = blockIdx.x, tid = threadIdx.x;
    const float* p = S + (size_t)row * ncols;
    float m = -1e30f;
    for (int j = tid; j < ncols; j += 256) m = fmaxf(m, p[j]);
    sb[tid] = m; __syncthreads();
    for (int s = 128; s > 0; s >>= 1) { if (tid < s) sb[tid] = fmaxf(sb[tid], sb[tid + s]); __syncthreads(); }
    m = sb[0]; __syncthreads();
    float s = 0;
    for (int j = tid; j < ncols; j += 256) s += __expf(p[j] - m);
    sb[tid] = s; __syncthreads();
    for (int st = 128; st > 0; st >>= 1) { if (tid < st) sb[tid] += sb[tid + st]; __syncthreads(); }
    if (tid == 0) { rm[row] = m; rs[row] = sb[0]; }
}

// ---------------- per-col max & sumexp ----------------
__global__ void colstats_kernel(const float* __restrict__ S, float* __restrict__ cm,
                                float* __restrict__ cs, int nrows) {
    int mat = blockIdx.y;
    int j = blockIdx.x * 256 + threadIdx.x;
    const float* p = S + (size_t)mat * nrows * NN + j;
    float m = -1e30f;
    for (int i = 0; i < nrows; ++i) m = fmaxf(m, p[(size_t)i * NN]);
    float s = 0;
    for (int i = 0; i < nrows; ++i) s += __expf(p[(size_t)i * NN] - m);
    cm[(size_t)mat * NN + j] = m;
    cs[(size_t)mat * NN + j] = s;
}

// ---------------- LN (over 512) + exact GELU: bf16 in, bf16 out ----------------
__global__ void ln_gelu_b(const u16* __restrict__ hb, const float* __restrict__ g,
                          const float* __restrict__ be, u16* __restrict__ out) {
    __shared__ float sb[256];
    int row = blockIdx.x, tid = threadIdx.x;
    const u16* p = hb + (size_t)row * 512;
    float x0 = b2f(p[tid]), x1 = b2f(p[tid + 256]);
    sb[tid] = x0 + x1; __syncthreads();
    for (int s = 128; s > 0; s >>= 1) { if (tid < s) sb[tid] += sb[tid + s]; __syncthreads(); }
    float mu = sb[0] * (1.f / 512.f); __syncthreads();
    float d0 = x0 - mu, d1 = x1 - mu;
    sb[tid] = d0 * d0 + d1 * d1; __syncthreads();
    for (int s = 128; s > 0; s >>= 1) { if (tid < s) sb[tid] += sb[tid + s]; __syncthreads(); }
    float rstd = rsqrtf(sb[0] * (1.f / 512.f) + 1e-5f);
    float y0 = d0 * rstd * g[tid] + be[tid];
    float y1 = d1 * rstd * g[tid + 256] + be[tid + 256];
    out[(size_t)row * 512 + tid]       = f2b(0.5f * y0 * (1.f + erff(y0 * 0.70710678118654752f)));
    out[(size_t)row * 512 + tid + 256] = f2b(0.5f * y1 * (1.f + erff(y1 * 0.70710678118654752f)));
}

// ---------------- z = x @ Wm + bm ----------------
__global__ void zproj_kernel(const float* __restrict__ X, const float* __restrict__ Wm,
                             const float* __restrict__ bm, float* __restrict__ z) {
    __shared__ float sb[256];
    int row = blockIdx.x, tid = threadIdx.x;
    float v = X[(size_t)row * 256 + tid] * Wm[tid];
    sb[tid] = v; __syncthreads();
    for (int s = 128; s > 0; s >>= 1) { if (tid < s) sb[tid] += sb[tid + s]; __syncthreads(); }
    if (tid == 0) z[row] = sb[0] + bm[0];
}

// ---------------- final assemble of [B, N+1, N+1] ----------------
__global__ void assemble_kernel(const float* __restrict__ sim2, const float* __restrict__ z0,
                                const float* __restrict__ z1, const float* __restrict__ rm,
                                const float* __restrict__ rs, const float* __restrict__ cm,
                                const float* __restrict__ cs, float* __restrict__ out) {
    int idx = blockIdx.x * 256 + threadIdx.x;
    if (idx >= NB * NP * NP) return;
    int b = idx / (NP * NP);
    int rem = idx - b * NP * NP;
    int i = rem / NP, j = rem - i * NP;
    float v;
    if (i < NN && j < NN) {
        float s = sim2[((size_t)b * NN + i) * NN + j];
        float lr = s - rm[b * NN + i] - logf(rs[b * NN + i]);
        float lc = s - cm[b * NN + j] - logf(cs[b * NN + j]);
        v = lr + lc + logsigf(z0[b * NN + i]) + logsigf(z1[b * NN + j]);
    } else if (i < NN) {
        v = logsigf(-z0[b * NN + i]);
    } else if (j < NN) {
        v = logsigf(-z1[b * NN + j]);
    } else {
        v = 0.f;
    }
    out[idx] = v;
}

extern "C" void kernel_launch(void* const* d_in, const int* in_sizes, int n_in,
                              void* d_out, int out_size, void* d_ws, size_t ws_size,
                              hipStream_t stream) {
    auto in = [&](int i) { return (const float*)d_in[i]; };
    const float* kpts0 = in(0);
    const float* kpts1 = in(1);
    const float* desc0 = in(2);
    const float* desc1 = in(3);
    const float* fx = in(4);
    const float* fy = in(5);
    const float* sWqk = in(6);  const float* sbqk = in(7);
    const float* sWv  = in(8);  const float* sbv  = in(9);
    const float* sWo  = in(10); const float* sbo  = in(11);
    const float* sW1  = in(12); const float* sb1  = in(13);
    const float* sg   = in(14); const float* sbe  = in(15);
    const float* sW2  = in(16); const float* sb2  = in(17);
    const float* cWqk = in(18); const float* cbqk = in(19);
    const float* cWv  = in(20); const float* cbv  = in(21);
    const float* cWo  = in(22); const float* cbo  = in(23);
    const float* cW1  = in(24); const float* cb1  = in(25);
    const float* cg   = in(26); const float* cbe  = in(27);
    const float* cW2  = in(28); const float* cb2  = in(29);
    const float* Wp = in(30); const float* bp = in(31);
    const float* Wm = in(32); const float* bm = in(33);

    const int Mst = 2 * NB * NN;               // 4096 stacked rows
    const size_t SND = (size_t)Mst * ND;       // 1M elems

    char* base = (char*)d_ws;
    size_t off = 0;
    auto allocf = [&](size_t n) { float* p = (float*)(base + off); off += ((n * 4 + 255) & ~(size_t)255); return p; };
    auto allocb = [&](size_t n) { u16* p = (u16*)(base + off);   off += ((n * 2 + 255) & ~(size_t)255); return p; };

    float* x    = allocf(SND);                       // fp32 residual stream (stacked)
    float* cst  = allocf((size_t)Mst * 64);
    float* snt  = allocf((size_t)Mst * 64);
    float* simb = allocf((size_t)NB * NN * NN);      // 8.4 MB
    float* z    = allocf(Mst);
    float* st0  = allocf(2048);
    float* st1  = allocf(2048);
    float* st2  = allocf(2048);
    float* st3  = allocf(2048);
    float* bqvs = allocf((size_t)NL * 512);
    float* bqvc = allocf((size_t)NL * 512);

    u16* xb    = allocb(SND);
    u16* tQVb  = allocb((size_t)Mst * 512);
    u16* attnb = allocb(SND);
    u16* mb    = allocb(SND);
    u16* hb    = allocb((size_t)Mst * 512);
    u16* hgb   = allocb((size_t)Mst * 512);
    u16* wsqv = allocb((size_t)NL * 512 * 256);
    u16* wso  = allocb((size_t)NL * 256 * 256);
    u16* wsw1 = allocb((size_t)NL * 512 * 512);
    u16* wsw2 = allocb((size_t)NL * 512 * 256);
    u16* wcqv = allocb((size_t)NL * 512 * 256);
    u16* wco  = allocb((size_t)NL * 256 * 256);
    u16* wcw1 = allocb((size_t)NL * 512 * 512);
    u16* wcw2 = allocb((size_t)NL * 512 * 256);
    u16* wpb  = allocb((size_t)256 * 256);

    // ---- weight conversion ----
    auto wconv = [&](const float* w, u16* wt, int K, int N, int Lz, size_t outZ) {
        wconv_kernel<<<dim3(N / 32, K / 32, Lz), dim3(32, 8), 0, stream>>>(w, wt, K, N, outZ);
    };
    wconv(sWqk, wsqv,             256, 256, NL, 512 * 256);
    wconv(sWv,  wsqv + 256 * 256, 256, 256, NL, 512 * 256);
    wconv(cWqk, wcqv,             256, 256, NL, 512 * 256);
    wconv(cWv,  wcqv + 256 * 256, 256, 256, NL, 512 * 256);
    wconv(sWo, wso, 256, 256, NL, 256 * 256);
    wconv(cWo, wco, 256, 256, NL, 256 * 256);
    wconv(sW1, wsw1, 512, 512, NL, 512 * 512);
    wconv(cW1, wcw1, 512, 512, NL, 512 * 512);
    wconv(sW2, wsw2, 512, 256, NL, 512 * 256);
    wconv(cW2, wcw2, 512, 256, NL, 512 * 256);
    wconv(Wp, wpb, 256, 256, 1, 256 * 256);
    biaspack_kernel<<<(NL * 512 + 255) / 256, 256, 0, stream>>>(sbqk, sbv, bqvs, NL);
    biaspack_kernel<<<(NL * 512 + 255) / 256, 256, 0, stream>>>(cbqk, cbv, bqvc, NL);

    rope_cs_kernel<<<512, 256, 0, stream>>>(kpts0, fx, fy, cst, snt);
    rope_cs_kernel<<<512, 256, 0, stream>>>(kpts1, fx, fy, cst + 2048 * 64, snt + 2048 * 64);
    copyconv_kernel<<<2048, 256, 0, stream>>>(desc0, x, xb, (int)(SND / 2));
    copyconv_kernel<<<2048, 256, 0, stream>>>(desc1, x + SND / 2, xb + SND / 2, (int)(SND / 2));

    auto gemm = [&](const u16* A, const u16* A2, const u16* Bt, const float* bias,
                    const float* res, float* Cf, u16* Cb, int N, int K, float scale,
                    const float* csp, const float* snp) {
        gemm_mfma<<<dim3(N / 64, Mst / 64), 256, 0, stream>>>(A, A2, Bt, bias, res, Cf, Cb,
                                                              Mst, N, K, scale, csp, snp);
    };

    for (int i = 0; i < NL; ++i) {
        const size_t oQV = (size_t)i * 512 * 256;
        const size_t oDD = (size_t)i * 256 * 256;
        const size_t oW1 = (size_t)i * 512 * 512;
        const size_t oW2 = (size_t)i * 512 * 256;

        // ---- self (both tensors stacked) ----
        gemm(xb, nullptr, wsqv + oQV, bqvs + i * 512, nullptr, nullptr, tQVb, 512, 256, 1.f, cst, snt);
        flash_kernel<<<dim3(16, 16), 256, 0, stream>>>(tQVb, 512, tQVb + 256, 512, attnb, 0.125f, 0);
        gemm(attnb, nullptr, wso + oDD, sbo + i * ND, nullptr, nullptr, mb, 256, 256, 1.f, nullptr, nullptr);
        gemm(xb, mb, wsw1 + oW1, sb1 + i * 512, nullptr, nullptr, hb, 512, 512, 1.f, nullptr, nullptr);
        ln_gelu_b<<<Mst, 256, 0, stream>>>(hb, sg + i * 512, sbe + i * 512, hgb);
        gemm(hgb, nullptr, wsw2 + oW2, sb2 + i * ND, x, x, xb, 256, 512, 1.f, nullptr, nullptr);

        // ---- cross (both directions stacked; no rope, scale in flash) ----
        gemm(xb, nullptr, wcqv + oQV, bqvc + i * 512, nullptr, nullptr, tQVb, 512, 256, 1.f, nullptr, nullptr);
        flash_kernel<<<dim3(16, 16), 256, 0, stream>>>(tQVb, 512, tQVb + 256, 512, attnb, 0.125f, 1);
        gemm(attnb, nullptr, wco + oDD, cbo + i * ND, nullptr, nullptr, mb, 256, 256, 1.f, nullptr, nullptr);
        gemm(xb, mb, wcw1 + oW1, cb1 + i * 512, nullptr, nullptr, hb, 512, 512, 1.f, nullptr, nullptr);
        ln_gelu_b<<<Mst, 256, 0, stream>>>(hb, cg + i * 512, cbe + i * 512, hgb);
        gemm(hgb, nullptr, wcw2 + oW2, cb2 + i * ND, x, x, xb, 256, 512, 1.f, nullptr, nullptr);
    }

    // ---- match head ----
    gemm(xb, nullptr, wpb, bp, nullptr, nullptr, attnb, 256, 256, 0.25f, nullptr, nullptr);  // md (stacked)
    zproj_kernel<<<Mst, 256, 0, stream>>>(x, Wm, bm, z);
    scores_mfma<<<dim3(16, 16, NB), 256, 0, stream>>>(attnb, attnb + (size_t)2048 * 256, simb,
                                                      1, 256, 256, 1.f);
    rowstats_kernel<<<NB * NN, 256, 0, stream>>>(simb, st0, st1, NN);
    colstats_kernel<<<dim3(NN / 256, NB), 256, 0, stream>>>(simb, st2, st3, NN);
    int total = NB * NP * NP;
    assemble_kernel<<<(total + 255) / 256, 256, 0, stream>>>(simb, z, z + 2048, st0, st1,
                                                             st2, st3, (float*)d_out);
}

// Round 4
// 1185.454 us; speedup vs baseline: 7.4542x; 1.5069x over previous
//
#include <hip/hip_runtime.h>
#include <hip/hip_bf16.h>
#include <math.h>

#define NB 2
#define NN 1024
#define ND 256
#define NHD 4
#define NL 6
#define NP (NN + 1)

typedef unsigned short u16;
typedef __attribute__((ext_vector_type(8))) short bf16x8;
typedef __attribute__((ext_vector_type(4))) float f32x4;

__device__ __forceinline__ u16 f2b(float f) {
    union { float f; unsigned u; } v; v.f = f;
    unsigned r = v.u + 0x7FFFu + ((v.u >> 16) & 1u);
    return (u16)(r >> 16);
}
__device__ __forceinline__ float b2f(u16 b) {
    union { unsigned u; float f; } v; v.u = ((unsigned)b) << 16;
    return v.f;
}
__device__ __forceinline__ float logsigf(float x) {
    return (x >= 0.f) ? -log1pf(expf(-x)) : (x - log1pf(expf(x)));
}

// ---------------- RoPE tables ----------------
__global__ void rope_cs_kernel(const float* __restrict__ kpts, const float* __restrict__ fx,
                               const float* __restrict__ fy, float* __restrict__ cs,
                               float* __restrict__ sn) {
    int idx = blockIdx.x * 256 + threadIdx.x;      // 2048*64
    int row = idx >> 6, j = idx & 63;
    float kx = kpts[row * 2], ky = kpts[row * 2 + 1];
    float f;
    if (j < 32) f = ((kx - 512.f) * (1.f / 512.f)) * fx[j >> 1];
    else        f = ((ky - 384.f) * (1.f / 512.f)) * fy[(j - 32) >> 1];
    cs[idx] = cosf(f);
    sn[idx] = sinf(f);
}

__global__ void copyconv_kernel(const float* __restrict__ in, float* __restrict__ outf,
                                u16* __restrict__ outb, int n) {
    int i = blockIdx.x * 256 + threadIdx.x;
    if (i < n) { float v = in[i]; outf[i] = v; outb[i] = f2b(v); }
}

// weight convert + transpose: [Lz][K][N] f32 -> [Lz(outZ)][N][K] bf16
__global__ void wconv_kernel(const float* __restrict__ in, u16* __restrict__ out, int K, int N,
                             size_t outZ) {
    __shared__ float t[32][33];
    int z = blockIdx.z;
    int k0 = blockIdx.y * 32, n0 = blockIdx.x * 32;
    const float* W = in + (size_t)z * K * N;
    u16* Wt = out + (size_t)z * outZ;
    int tx = threadIdx.x, ty = threadIdx.y;  // 32 x 8
    for (int i = 0; i < 32; i += 8)
        t[ty + i][tx] = W[(size_t)(k0 + ty + i) * N + n0 + tx];
    __syncthreads();
    for (int i = 0; i < 32; i += 8)
        Wt[(size_t)(n0 + ty + i) * K + k0 + tx] = f2b(t[tx][ty + i]);
}

__global__ void biaspack_kernel(const float* __restrict__ b0, const float* __restrict__ b1,
                                float* __restrict__ out, int L) {
    int idx = blockIdx.x * 256 + threadIdx.x;
    if (idx >= L * 512) return;
    int i = idx >> 9, c = idx & 511;
    out[idx] = (c < 256) ? b0[i * 256 + c] : b1[i * 256 + c - 256];
}

// ======= GEMM: BK=64, double-buffered LDS, one barrier/iter =======
// C = rope?((A@B + bias)) * scale_c + res; A [M][K] bf16 (A2: concat halves), Bt [N][K] bf16
__global__ __launch_bounds__(256)
void gemm_mfma(const u16* __restrict__ A, const u16* __restrict__ A2,
               const u16* __restrict__ Bt, const float* __restrict__ bias,
               const float* __restrict__ res, float* __restrict__ Cf, u16* __restrict__ Cb,
               int M, int N, int K, float scale_lo, float scale_hi,
               const float* __restrict__ csp, const float* __restrict__ snp) {
    __shared__ u16 As[2][64 * 72];
    __shared__ u16 Bs[2][64 * 72];
    int tid = threadIdx.x;
    int lane = tid & 63, wave = tid >> 6;
    int row0 = blockIdx.y * 64, col0 = blockIdx.x * 64;
    int wm = (wave >> 1) * 32, wn = (wave & 1) * 32;
    int l15 = lane & 15, l4 = lane >> 4;
    f32x4 acc[2][2] = {};
    int srl = tid >> 3, sc8 = (tid & 7) * 8;   // staging row-low / col8

    auto loadA = [&](int k0, int it) -> bf16x8 {
        int rr = row0 + srl + it * 32;
        int kg = k0 + sc8;
        const u16* src;
        if (A2) src = (kg < 256) ? &A[(size_t)rr * 256 + kg] : &A2[(size_t)rr * 256 + kg - 256];
        else    src = &A[(size_t)rr * K + kg];
        return *(const bf16x8*)src;
    };
    auto loadB = [&](int k0, int it) -> bf16x8 {
        return *(const bf16x8*)&Bt[(size_t)(col0 + srl + it * 32) * K + k0 + sc8];
    };

    bf16x8 rA0 = loadA(0, 0), rA1 = loadA(0, 1);
    bf16x8 rB0 = loadB(0, 0), rB1 = loadB(0, 1);
    *(bf16x8*)&As[0][srl * 72 + sc8] = rA0;
    *(bf16x8*)&As[0][(srl + 32) * 72 + sc8] = rA1;
    *(bf16x8*)&Bs[0][srl * 72 + sc8] = rB0;
    *(bf16x8*)&Bs[0][(srl + 32) * 72 + sc8] = rB1;
    __syncthreads();

    int nt = K >> 6;
    for (int t = 0; t < nt; ++t) {
        int buf = t & 1;
        bool more = (t + 1) < nt;
        if (more) {
            rA0 = loadA((t + 1) * 64, 0); rA1 = loadA((t + 1) * 64, 1);
            rB0 = loadB((t + 1) * 64, 0); rB1 = loadB((t + 1) * 64, 1);
        }
#pragma unroll
        for (int ks = 0; ks < 2; ++ks) {
            bf16x8 a0 = *(bf16x8*)&As[buf][(wm + l15) * 72 + ks * 32 + l4 * 8];
            bf16x8 a1 = *(bf16x8*)&As[buf][(wm + 16 + l15) * 72 + ks * 32 + l4 * 8];
            bf16x8 b0 = *(bf16x8*)&Bs[buf][(wn + l15) * 72 + ks * 32 + l4 * 8];
            bf16x8 b1 = *(bf16x8*)&Bs[buf][(wn + 16 + l15) * 72 + ks * 32 + l4 * 8];
            acc[0][0] = __builtin_amdgcn_mfma_f32_16x16x32_bf16(a0, b0, acc[0][0], 0, 0, 0);
            acc[0][1] = __builtin_amdgcn_mfma_f32_16x16x32_bf16(a0, b1, acc[0][1], 0, 0, 0);
            acc[1][0] = __builtin_amdgcn_mfma_f32_16x16x32_bf16(a1, b0, acc[1][0], 0, 0, 0);
            acc[1][1] = __builtin_amdgcn_mfma_f32_16x16x32_bf16(a1, b1, acc[1][1], 0, 0, 0);
        }
        if (more) {
            int nb = buf ^ 1;
            *(bf16x8*)&As[nb][srl * 72 + sc8] = rA0;
            *(bf16x8*)&As[nb][(srl + 32) * 72 + sc8] = rA1;
            *(bf16x8*)&Bs[nb][srl * 72 + sc8] = rB0;
            *(bf16x8*)&Bs[nb][(srl + 32) * 72 + sc8] = rB1;
        }
        __syncthreads();
    }
#pragma unroll
    for (int mi = 0; mi < 2; ++mi)
#pragma unroll
        for (int ni = 0; ni < 2; ++ni)
#pragma unroll
            for (int j = 0; j < 4; ++j) {
                int r = row0 + wm + mi * 16 + l4 * 4 + j;
                int c = col0 + wn + ni * 16 + l15;
                float v = acc[mi][ni][j] + (bias ? bias[c] : 0.f);
                float pn = __shfl_xor(v, 1);    // partner column (c^1)
                if (csp && c < 256) {
                    float cc = csp[(size_t)r * 64 + (c & 63)];
                    float ss = snp[(size_t)r * 64 + (c & 63)];
                    v = (c & 1) ? (v * cc + pn * ss) : (v * cc - pn * ss);
                }
                v *= (c < 256) ? scale_lo : scale_hi;
                if (res) v += res[(size_t)r * N + c];
                if (Cf) Cf[(size_t)r * N + c] = v;
                if (Cb) Cb[(size_t)r * N + c] = f2b(v);
            }
}

// ======= flash attention, dbuf K/V, tr-read V, permuted P =======
#define QSTR 72
#define VDSTR 1032                 // u16 per dblk (64*16 + 8 pad)
#define VBUFE (4 * VDSTR)

__global__ __launch_bounds__(256)
void flash_kernel(const u16* __restrict__ Qp, const u16* __restrict__ Vp,
                  u16* __restrict__ Ob, int kswap) {
    __shared__ u16 Qs[64 * QSTR];
    __shared__ u16 Ks[2][64 * QSTR];
    __shared__ u16 Vs[2][VBUFE];
    __shared__ u16 Ps[64 * QSTR];
    int y = blockIdx.y;
    int t = y >> 3, b = (y >> 2) & 1, h = y & 3;
    int qR = t * 2048 + b * 1024;
    int kt = kswap ? (1 - t) : t;
    int kR = kt * 2048 + b * 1024;
    int i0 = blockIdx.x * 64;
    int tid = threadIdx.x, lane = tid & 63, wave = tid >> 6;
    int l15 = lane & 15, l4 = lane >> 4;
    int wm = wave * 16;
    int srl = tid >> 3, sc8 = (tid & 7) * 8;

    const u16* Qbase = Qp + (size_t)(qR + i0) * 512 + h * 64;
    const u16* Kbase = Qp + (size_t)kR * 512 + h * 64;
    const u16* Vbase = Vp + (size_t)kR * 512 + h * 64;

    // stage Q + first K/V tile
#pragma unroll
    for (int it = 0; it < 2; ++it) {
        int rr = srl + it * 32;
        *(bf16x8*)&Qs[rr * QSTR + sc8] = *(const bf16x8*)&Qbase[(size_t)rr * 512 + sc8];
        *(bf16x8*)&Ks[0][rr * QSTR + sc8] = *(const bf16x8*)&Kbase[(size_t)rr * 512 + sc8];
        bf16x8 v = *(const bf16x8*)&Vbase[(size_t)rr * 512 + sc8];
        *(bf16x8*)&Vs[0][(sc8 >> 4) * VDSTR + rr * 16 + (sc8 & 15)] = v;
    }
    __syncthreads();

    float m[4], l[4];
    f32x4 accO[4] = {};
#pragma unroll
    for (int j = 0; j < 4; ++j) { m[j] = -1e30f; l[j] = 0.f; }

    for (int j0 = 0; j0 < NN; j0 += 64) {
        int buf = (j0 >> 6) & 1;
        bool more = (j0 + 64) < NN;
        bf16x8 nK0, nK1, nV0, nV1;
        if (more) {
            nK0 = *(const bf16x8*)&Kbase[(size_t)(j0 + 64 + srl) * 512 + sc8];
            nK1 = *(const bf16x8*)&Kbase[(size_t)(j0 + 96 + srl) * 512 + sc8];
            nV0 = *(const bf16x8*)&Vbase[(size_t)(j0 + 64 + srl) * 512 + sc8];
            nV1 = *(const bf16x8*)&Vbase[(size_t)(j0 + 96 + srl) * 512 + sc8];
        }
        // --- QK^T (16 q rows per wave x 64 kv) ---
        f32x4 accS[4] = {};
#pragma unroll
        for (int ks = 0; ks < 2; ++ks) {
            bf16x8 a = *(bf16x8*)&Qs[(wm + l15) * QSTR + ks * 32 + l4 * 8];
#pragma unroll
            for (int n = 0; n < 4; ++n) {
                bf16x8 bb = *(bf16x8*)&Ks[buf][(n * 16 + l15) * QSTR + ks * 32 + l4 * 8];
                accS[n] = __builtin_amdgcn_mfma_f32_16x16x32_bf16(a, bb, accS[n], 0, 0, 0);
            }
        }
        // --- online softmax (scale pre-folded into q,k) ---
        float p[4][4];
#pragma unroll
        for (int j = 0; j < 4; ++j) {
            float tm = fmaxf(fmaxf(accS[0][j], accS[1][j]), fmaxf(accS[2][j], accS[3][j]));
#pragma unroll
            for (int d = 1; d < 16; d <<= 1) tm = fmaxf(tm, __shfl_xor(tm, d));
            float mnew = fmaxf(m[j], tm);
            float rr = __expf(m[j] - mnew);
            float ts = 0.f;
#pragma unroll
            for (int n = 0; n < 4; ++n) {
                float pv = __expf(accS[n][j] - mnew);
                p[n][j] = pv; ts += pv;
            }
#pragma unroll
            for (int d = 1; d < 16; d <<= 1) ts += __shfl_xor(ts, d);
            l[j] = l[j] * rr + ts;
            m[j] = mnew;
#pragma unroll
            for (int n = 0; n < 4; ++n) accO[n][j] *= rr;
        }
        // --- store P with k-permutation matching tr-read order ---
#pragma unroll
        for (int n = 0; n < 4; ++n) {
            int kv = n * 16 + l15;
            int c = (kv & 32) + (((kv >> 2) & 3) << 3) + (((kv >> 4) & 1) << 2) + (kv & 3);
#pragma unroll
            for (int j = 0; j < 4; ++j)
                Ps[(wm + l4 * 4 + j) * QSTR + c] = f2b(p[n][j]);
        }
        // --- PV: B-operand via hardware transpose read ---
#pragma unroll
        for (int ks = 0; ks < 2; ++ks) {
            bf16x8 a = *(bf16x8*)&Ps[(wm + l15) * QSTR + ks * 32 + l4 * 8];
#pragma unroll
            for (int n = 0; n < 4; ++n) {
                unsigned va = (unsigned)(size_t)(&Vs[buf][n * VDSTR]) + ks * 1024 + lane * 8;
                unsigned long long q0, q1;
                asm volatile("ds_read_b64_tr_b16 %0, %2\n\t"
                             "ds_read_b64_tr_b16 %1, %2 offset:512\n\t"
                             "s_waitcnt lgkmcnt(0)"
                             : "=&v"(q0), "=&v"(q1) : "v"(va) : "memory");
                union { unsigned long long q[2]; bf16x8 v; } uu;
                uu.q[0] = q0; uu.q[1] = q1;
                accO[n] = __builtin_amdgcn_mfma_f32_16x16x32_bf16(a, uu.v, accO[n], 0, 0, 0);
            }
        }
        // --- write next K/V tile ---
        if (more) {
            int nb = buf ^ 1;
            *(bf16x8*)&Ks[nb][srl * QSTR + sc8] = nK0;
            *(bf16x8*)&Ks[nb][(srl + 32) * QSTR + sc8] = nK1;
            *(bf16x8*)&Vs[nb][(sc8 >> 4) * VDSTR + srl * 16 + (sc8 & 15)] = nV0;
            *(bf16x8*)&Vs[nb][(sc8 >> 4) * VDSTR + (srl + 32) * 16 + (sc8 & 15)] = nV1;
        }
        __syncthreads();
    }
#pragma unroll
    for (int n = 0; n < 4; ++n)
#pragma unroll
        for (int j = 0; j < 4; ++j) {
            int r = i0 + wm + l4 * 4 + j;
            int d = n * 16 + l15;
            Ob[(size_t)(qR + r) * ND + h * 64 + d] = f2b(accO[n][j] / l[j]);
        }
}

// ---------------- per-row max & sumexp ----------------
__global__ void rowstats_kernel(const float* __restrict__ S, float* __restrict__ rm,
                                float* __restrict__ rs, int ncols) {
    __shared__ float sb[256];
    int row = blockIdx.x, tid = threadIdx.x;
    const float* p = S + (size_t)row * ncols;
    float m = -1e30f;
    for (int j = tid; j < ncols; j += 256) m = fmaxf(m, p[j]);
    sb[tid] = m; __syncthreads();
    for (int s = 128; s > 0; s >>= 1) { if (tid < s) sb[tid] = fmaxf(sb[tid], sb[tid + s]); __syncthreads(); }
    m = sb[0]; __syncthreads();
    float s = 0;
    for (int j = tid; j < ncols; j += 256) s += __expf(p[j] - m);
    sb[tid] = s; __syncthreads();
    for (int st = 128; st > 0; st >>= 1) { if (tid < st) sb[tid] += sb[tid + st]; __syncthreads(); }
    if (tid == 0) { rm[row] = m; rs[row] = sb[0]; }
}

// ---------------- column stats: partial over row-chunks, then reduce ----------------
#define CSCH 8
__global__ void colstats_part(const float* __restrict__ S, float* __restrict__ pm,
                              float* __restrict__ ps) {
    int mat = blockIdx.z;
    int j = blockIdx.x * 256 + threadIdx.x;
    int r0 = blockIdx.y * (NN / CSCH);
    const float* p = S + (size_t)mat * NN * NN + (size_t)r0 * NN + j;
    float m = -1e30f;
    for (int i = 0; i < NN / CSCH; ++i) m = fmaxf(m, p[(size_t)i * NN]);
    float s = 0;
    for (int i = 0; i < NN / CSCH; ++i) s += __expf(p[(size_t)i * NN] - m);
    int o = (mat * CSCH + blockIdx.y) * NN + j;
    pm[o] = m; ps[o] = s;
}
__global__ void colstats_red(const float* __restrict__ pm, const float* __restrict__ ps,
                             float* __restrict__ cm, float* __restrict__ cs) {
    int idx = blockIdx.x * 256 + threadIdx.x;  // mat*NN + j
    int mat = idx >> 10, j = idx & 1023;
    float m = -1e30f;
#pragma unroll
    for (int k = 0; k < CSCH; ++k) m = fmaxf(m, pm[(mat * CSCH + k) * NN + j]);
    float s = 0;
#pragma unroll
    for (int k = 0; k < CSCH; ++k)
        s += ps[(mat * CSCH + k) * NN + j] * __expf(pm[(mat * CSCH + k) * NN + j] - m);
    cm[idx] = m; cs[idx] = s;
}

// ---------------- LN (512) + exact GELU: bf16 in/out ----------------
__global__ void ln_gelu_b(const u16* __restrict__ hb, const float* __restrict__ g,
                          const float* __restrict__ be, u16* __restrict__ out) {
    __shared__ float sb[256];
    int row = blockIdx.x, tid = threadIdx.x;
    const u16* p = hb + (size_t)row * 512;
    float x0 = b2f(p[tid]), x1 = b2f(p[tid + 256]);
    sb[tid] = x0 + x1; __syncthreads();
    for (int s = 128; s > 0; s >>= 1) { if (tid < s) sb[tid] += sb[tid + s]; __syncthreads(); }
    float mu = sb[0] * (1.f / 512.f); __syncthreads();
    float d0 = x0 - mu, d1 = x1 - mu;
    sb[tid] = d0 * d0 + d1 * d1; __syncthreads();
    for (int s = 128; s > 0; s >>= 1) { if (tid < s) sb[tid] += sb[tid + s]; __syncthreads(); }
    float rstd = rsqrtf(sb[0] * (1.f / 512.f) + 1e-5f);
    float y0 = d0 * rstd * g[tid] + be[tid];
    float y1 = d1 * rstd * g[tid + 256] + be[tid + 256];
    out[(size_t)row * 512 + tid]       = f2b(0.5f * y0 * (1.f + erff(y0 * 0.70710678118654752f)));
    out[(size_t)row * 512 + tid + 256] = f2b(0.5f * y1 * (1.f + erff(y1 * 0.70710678118654752f)));
}

// ---------------- z = x @ Wm + bm ----------------
__global__ void zproj_kernel(const float* __restrict__ X, const float* __restrict__ Wm,
                             const float* __restrict__ bm, float* __restrict__ z) {
    __shared__ float sb[256];
    int row = blockIdx.x, tid = threadIdx.x;
    float v = X[(size_t)row * 256 + tid] * Wm[tid];
    sb[tid] = v; __syncthreads();
    for (int s = 128; s > 0; s >>= 1) { if (tid < s) sb[tid] += sb[tid + s]; __syncthreads(); }
    if (tid == 0) z[row] = sb[0] + bm[0];
}

// ---------------- final assemble ----------------
__global__ void assemble_kernel(const float* __restrict__ sim2, const float* __restrict__ z0,
                                const float* __restrict__ z1, const float* __restrict__ rm,
                                const float* __restrict__ rs, const float* __restrict__ cm,
                                const float* __restrict__ cs, float* __restrict__ out) {
    int idx = blockIdx.x * 256 + threadIdx.x;
    if (idx >= NB * NP * NP) return;
    int b = idx / (NP * NP);
    int rem = idx - b * NP * NP;
    int i = rem / NP, j = rem - i * NP;
    float v;
    if (i < NN && j < NN) {
        float s = sim2[((size_t)b * NN + i) * NN + j];
        float lr = s - rm[b * NN + i] - logf(rs[b * NN + i]);
        float lc = s - cm[b * NN + j] - logf(cs[b * NN + j]);
        v = lr + lc + logsigf(z0[b * NN + i]) + logsigf(z1[b * NN + j]);
    } else if (i < NN) {
        v = logsigf(-z0[b * NN + i]);
    } else if (j < NN) {
        v = logsigf(-z1[b * NN + j]);
    } else {
        v = 0.f;
    }
    out[idx] = v;
}

extern "C" void kernel_launch(void* const* d_in, const int* in_sizes, int n_in,
                              void* d_out, int out_size, void* d_ws, size_t ws_size,
                              hipStream_t stream) {
    auto in = [&](int i) { return (const float*)d_in[i]; };
    const float* kpts0 = in(0);
    const float* kpts1 = in(1);
    const float* desc0 = in(2);
    const float* desc1 = in(3);
    const float* fx = in(4);
    const float* fy = in(5);
    const float* sWqk = in(6);  const float* sbqk = in(7);
    const float* sWv  = in(8);  const float* sbv  = in(9);
    const float* sWo  = in(10); const float* sbo  = in(11);
    const float* sW1  = in(12); const float* sb1  = in(13);
    const float* sg   = in(14); const float* sbe  = in(15);
    const float* sW2  = in(16); const float* sb2  = in(17);
    const float* cWqk = in(18); const float* cbqk = in(19);
    const float* cWv  = in(20); const float* cbv  = in(21);
    const float* cWo  = in(22); const float* cbo  = in(23);
    const float* cW1  = in(24); const float* cb1  = in(25);
    const float* cg   = in(26); const float* cbe  = in(27);
    const float* cW2  = in(28); const float* cb2  = in(29);
    const float* Wp = in(30); const float* bp = in(31);
    const float* Wm = in(32); const float* bm = in(33);

    const int Mst = 2 * NB * NN;               // 4096 stacked rows
    const size_t SND = (size_t)Mst * ND;

    char* base = (char*)d_ws;
    size_t off = 0;
    auto allocf = [&](size_t n) { float* p = (float*)(base + off); off += ((n * 4 + 255) & ~(size_t)255); return p; };
    auto allocb = [&](size_t n) { u16* p = (u16*)(base + off);   off += ((n * 2 + 255) & ~(size_t)255); return p; };

    float* x    = allocf(SND);
    float* cst  = allocf((size_t)Mst * 64);
    float* snt  = allocf((size_t)Mst * 64);
    float* simb = allocf((size_t)NB * NN * NN);
    float* z    = allocf(Mst);
    float* st0  = allocf(2048);
    float* st1  = allocf(2048);
    float* st2  = allocf(2048);
    float* st3  = allocf(2048);
    float* pm   = allocf((size_t)NB * CSCH * NN);
    float* ps   = allocf((size_t)NB * CSCH * NN);
    float* bqvs = allocf((size_t)NL * 512);
    float* bqvc = allocf((size_t)NL * 512);

    u16* xb    = allocb(SND);
    u16* tQVb  = allocb((size_t)Mst * 512);
    u16* attnb = allocb(SND);
    u16* mb    = allocb(SND);
    u16* hb    = allocb((size_t)Mst * 512);
    u16* hgb   = allocb((size_t)Mst * 512);
    u16* wsqv = allocb((size_t)NL * 512 * 256);
    u16* wso  = allocb((size_t)NL * 256 * 256);
    u16* wsw1 = allocb((size_t)NL * 512 * 512);
    u16* wsw2 = allocb((size_t)NL * 512 * 256);
    u16* wcqv = allocb((size_t)NL * 512 * 256);
    u16* wco  = allocb((size_t)NL * 256 * 256);
    u16* wcw1 = allocb((size_t)NL * 512 * 512);
    u16* wcw2 = allocb((size_t)NL * 512 * 256);
    u16* wpb  = allocb((size_t)256 * 256);

    auto wconv = [&](const float* w, u16* wt, int K, int N, int Lz, size_t outZ) {
        wconv_kernel<<<dim3(N / 32, K / 32, Lz), dim3(32, 8), 0, stream>>>(w, wt, K, N, outZ);
    };
    wconv(sWqk, wsqv,             256, 256, NL, 512 * 256);
    wconv(sWv,  wsqv + 256 * 256, 256, 256, NL, 512 * 256);
    wconv(cWqk, wcqv,             256, 256, NL, 512 * 256);
    wconv(cWv,  wcqv + 256 * 256, 256, 256, NL, 512 * 256);
    wconv(sWo, wso, 256, 256, NL, 256 * 256);
    wconv(cWo, wco, 256, 256, NL, 256 * 256);
    wconv(sW1, wsw1, 512, 512, NL, 512 * 512);
    wconv(cW1, wcw1, 512, 512, NL, 512 * 512);
    wconv(sW2, wsw2, 512, 256, NL, 512 * 256);
    wconv(cW2, wcw2, 512, 256, NL, 512 * 256);
    wconv(Wp, wpb, 256, 256, 1, 256 * 256);
    biaspack_kernel<<<(NL * 512 + 255) / 256, 256, 0, stream>>>(sbqk, sbv, bqvs, NL);
    biaspack_kernel<<<(NL * 512 + 255) / 256, 256, 0, stream>>>(cbqk, cbv, bqvc, NL);

    rope_cs_kernel<<<512, 256, 0, stream>>>(kpts0, fx, fy, cst, snt);
    rope_cs_kernel<<<512, 256, 0, stream>>>(kpts1, fx, fy, cst + 2048 * 64, snt + 2048 * 64);
    copyconv_kernel<<<2048, 256, 0, stream>>>(desc0, x, xb, (int)(SND / 2));
    copyconv_kernel<<<2048, 256, 0, stream>>>(desc1, x + SND / 2, xb + SND / 2, (int)(SND / 2));

    auto gemm = [&](const u16* A, const u16* A2, const u16* Bt, const float* bias,
                    const float* res, float* Cf, u16* Cb, int M, int N, int K,
                    float slo, float shi, const float* csp, const float* snp) {
        gemm_mfma<<<dim3(N / 64, M / 64), 256, 0, stream>>>(A, A2, Bt, bias, res, Cf, Cb,
                                                            M, N, K, slo, shi, csp, snp);
    };

    const float sc = 0.35355339059327379f;   // DH^-0.25 per side

    for (int i = 0; i < NL; ++i) {
        const size_t oQV = (size_t)i * 512 * 256;
        const size_t oDD = (size_t)i * 256 * 256;
        const size_t oW1 = (size_t)i * 512 * 512;
        const size_t oW2 = (size_t)i * 512 * 256;

        // ---- self ----
        gemm(xb, nullptr, wsqv + oQV, bqvs + i * 512, nullptr, nullptr, tQVb,
             Mst, 512, 256, sc, 1.f, cst, snt);
        flash_kernel<<<dim3(16, 16), 256, 0, stream>>>(tQVb, tQVb + 256, attnb, 0);
        gemm(attnb, nullptr, wso + oDD, sbo + i * ND, nullptr, nullptr, mb,
             Mst, 256, 256, 1.f, 1.f, nullptr, nullptr);
        gemm(xb, mb, wsw1 + oW1, sb1 + i * 512, nullptr, nullptr, hb,
             Mst, 512, 512, 1.f, 1.f, nullptr, nullptr);
        ln_gelu_b<<<Mst, 256, 0, stream>>>(hb, sg + i * 512, sbe + i * 512, hgb);
        gemm(hgb, nullptr, wsw2 + oW2, sb2 + i * ND, x, x, xb,
             Mst, 256, 512, 1.f, 1.f, nullptr, nullptr);

        // ---- cross ----
        gemm(xb, nullptr, wcqv + oQV, bqvc + i * 512, nullptr, nullptr, tQVb,
             Mst, 512, 256, sc, 1.f, nullptr, nullptr);
        flash_kernel<<<dim3(16, 16), 256, 0, stream>>>(tQVb, tQVb + 256, attnb, 1);
        gemm(attnb, nullptr, wco + oDD, cbo + i * ND, nullptr, nullptr, mb,
             Mst, 256, 256, 1.f, 1.f, nullptr, nullptr);
        gemm(xb, mb, wcw1 + oW1, cb1 + i * 512, nullptr, nullptr, hb,
             Mst, 512, 512, 1.f, 1.f, nullptr, nullptr);
        ln_gelu_b<<<Mst, 256, 0, stream>>>(hb, cg + i * 512, cbe + i * 512, hgb);
        gemm(hgb, nullptr, wcw2 + oW2, cb2 + i * ND, x, x, xb,
             Mst, 256, 512, 1.f, 1.f, nullptr, nullptr);
    }

    // ---- match head ----
    gemm(xb, nullptr, wpb, bp, nullptr, nullptr, attnb,
         Mst, 256, 256, 0.25f, 0.25f, nullptr, nullptr);          // md stacked
    zproj_kernel<<<Mst, 256, 0, stream>>>(x, Wm, bm, z);
    for (int b = 0; b < NB; ++b) {
        gemm(attnb + (size_t)b * 1024 * 256, nullptr,
             attnb + (size_t)(2048 + b * 1024) * 256, nullptr, nullptr,
             simb + (size_t)b * NN * NN, nullptr,
             1024, 1024, 256, 1.f, 1.f, nullptr, nullptr);
    }
    rowstats_kernel<<<NB * NN, 256, 0, stream>>>(simb, st0, st1, NN);
    colstats_part<<<dim3(NN / 256, CSCH, NB), 256, 0, stream>>>(simb, pm, ps);
    colstats_red<<<(NB * NN) / 256, 256, 0, stream>>>(pm, ps, st2, st3);
    int total = NB * NP * NP;
    assemble_kernel<<<(total + 255) / 256, 256, 0, stream>>>(simb, z, z + 2048, st0, st1,
                                                             st2, st3, (float*)d_out);
}